// Round 1
// baseline (789.090 us; speedup 1.0000x reference)
//
#include <hip/hip_runtime.h>
#include <hip/hip_bf16.h>
#include <math.h>

// Problem constants
#define BB 2
#define NN 2048
#define CC 768
#define NHEAD 12
#define HD 64
#define C3 2304

// ---------------- fp32 tiled GEMM: C = A @ B ----------------
// A: MxK row-major, B: KxN row-major, C: MxN row-major.
// 128x128 tile, BK=16, 256 threads, 8x8 micro-tile (split 4+4 at +64 offset
// so LDS reads are 2-way-bank-aliased at worst, which is free on CDNA4).
constexpr int GBM = 128, GBN = 128, GBK = 16;

__global__ __launch_bounds__(256) void sgemm_kernel(const float* __restrict__ A,
                                                    const float* __restrict__ B,
                                                    float* __restrict__ C,
                                                    int M, int Nn, int K) {
  __shared__ float As[GBK][GBM + 4];
  __shared__ float Bs[GBK][GBN + 4];
  const int tid = threadIdx.x;
  const int tx = tid & 15, ty = tid >> 4;
  const int m0 = blockIdx.y * GBM, n0 = blockIdx.x * GBN;

  float acc[8][8];
#pragma unroll
  for (int i = 0; i < 8; i++)
#pragma unroll
    for (int j = 0; j < 8; j++) acc[i][j] = 0.f;

  for (int k0 = 0; k0 < K; k0 += GBK) {
    // stage A tile (128 rows x 16 k), transposed into As[k][m]
#pragma unroll
    for (int l = 0; l < 2; l++) {
      int fid = tid + l * 256;
      int row = fid >> 2, c4 = (fid & 3) << 2;
      float4 v = *reinterpret_cast<const float4*>(&A[(size_t)(m0 + row) * K + k0 + c4]);
      As[c4 + 0][row] = v.x;
      As[c4 + 1][row] = v.y;
      As[c4 + 2][row] = v.z;
      As[c4 + 3][row] = v.w;
    }
    // stage B tile (16 k x 128 cols) direct
#pragma unroll
    for (int l = 0; l < 2; l++) {
      int fid = tid + l * 256;
      int row = fid >> 5, c4 = (fid & 31) << 2;
      *reinterpret_cast<float4*>(&Bs[row][c4]) =
          *reinterpret_cast<const float4*>(&B[(size_t)(k0 + row) * Nn + n0 + c4]);
    }
    __syncthreads();

#pragma unroll
    for (int kk = 0; kk < GBK; kk++) {
      float4 a0 = *reinterpret_cast<const float4*>(&As[kk][ty * 4]);
      float4 a1 = *reinterpret_cast<const float4*>(&As[kk][64 + ty * 4]);
      float4 b0 = *reinterpret_cast<const float4*>(&Bs[kk][tx * 4]);
      float4 b1 = *reinterpret_cast<const float4*>(&Bs[kk][64 + tx * 4]);
      float av[8] = {a0.x, a0.y, a0.z, a0.w, a1.x, a1.y, a1.z, a1.w};
      float bv[8] = {b0.x, b0.y, b0.z, b0.w, b1.x, b1.y, b1.z, b1.w};
#pragma unroll
      for (int i = 0; i < 8; i++)
#pragma unroll
        for (int j = 0; j < 8; j++) acc[i][j] = fmaf(av[i], bv[j], acc[i][j]);
    }
    __syncthreads();
  }

#pragma unroll
  for (int bi = 0; bi < 2; bi++)
#pragma unroll
    for (int i = 0; i < 4; i++) {
      int r = m0 + bi * 64 + ty * 4 + i;
#pragma unroll
      for (int bj = 0; bj < 2; bj++) {
        float4 v = make_float4(acc[bi * 4 + i][bj * 4 + 0], acc[bi * 4 + i][bj * 4 + 1],
                               acc[bi * 4 + i][bj * 4 + 2], acc[bi * 4 + i][bj * 4 + 3]);
        *reinterpret_cast<float4*>(&C[(size_t)r * Nn + n0 + bj * 64 + tx * 4]) = v;
      }
    }
}

// ---------------- RoPE + head-major scatter ----------------
// qkv: [B*N][2304] raw. Writes Q,K,V as [B*NHEAD][N][64] fp32.
__global__ __launch_bounds__(256) void rope_kernel(
    const float* __restrict__ qkv, const float* __restrict__ cos_t,
    const float* __restrict__ sin_t, const float* __restrict__ cos_h,
    const float* __restrict__ sin_h, const float* __restrict__ cos_w,
    const float* __restrict__ sin_w, const int* __restrict__ t_idx,
    const int* __restrict__ h_idx, const int* __restrict__ w_idx,
    float* __restrict__ Q, float* __restrict__ K, float* __restrict__ V) {
  const int tok = blockIdx.x;  // 0..B*N-1
  const int b = tok >> 11, n = tok & 2047;
  const int ti = t_idx[n], hi = h_idx[n], wi = w_idx[n];
  const float* base = qkv + (size_t)tok * C3;

#pragma unroll
  for (int s = 0; s < 3; s++) {
    int j = threadIdx.x + s * 256;
    float c, sn, sign;
    int pj;
    if (j < 192) {
      int jj = j;
      c = cos_t[ti * 192 + jj];
      sn = sin_t[ti * 192 + jj];
      pj = (jj < 96) ? j + 96 : j - 96;
      sign = (jj < 96) ? -1.f : 1.f;
    } else if (j < 480) {
      int jj = j - 192;
      c = cos_h[hi * 288 + jj];
      sn = sin_h[hi * 288 + jj];
      pj = (jj < 144) ? j + 144 : j - 144;
      sign = (jj < 144) ? -1.f : 1.f;
    } else {
      int jj = j - 480;
      c = cos_w[wi * 288 + jj];
      sn = sin_w[wi * 288 + jj];
      pj = (jj < 144) ? j + 144 : j - 144;
      sign = (jj < 144) ? -1.f : 1.f;
    }
    float qv = base[j], kv = base[768 + j], vv = base[1536 + j];
    float qp = base[pj] * sign, kp = base[768 + pj] * sign;
    int h = j >> 6, d = j & 63;
    size_t o = ((size_t)(b * NHEAD + h) * NN + n) * HD + d;
    Q[o] = fmaf(qv, c, qp * sn);
    K[o] = fmaf(kv, c, kp * sn);
    V[o] = vv;
  }
}

// ---------------- fp32 flash attention ----------------
// Q,K,V: [B*NHEAD][N][64]. Out: [B][N][C] (attn output, pre-projection).
// Block: 256 threads, one 64-row Q tile of one (b,h). Online softmax over
// 64-wide K tiles. LDS: Qs (transposed [d][r]), KPs (K transposed [d][c],
// reused for P transposed [kc][r]), Vs ([kc][d]).
__global__ __launch_bounds__(256) void attn_kernel(const float* __restrict__ Q,
                                                   const float* __restrict__ K,
                                                   const float* __restrict__ V,
                                                   float* __restrict__ Out) {
  __shared__ float Qs[64][68];
  __shared__ float KPs[64][68];
  __shared__ float Vs[64][68];
  const int tid = threadIdx.x;
  const int tx = tid & 15, ty = tid >> 4;
  const int qt = blockIdx.x;  // 0..31
  const int bh = blockIdx.y;  // 0..23
  const int b = bh / NHEAD, h = bh % NHEAD;
  const float* Qb = Q + (size_t)bh * NN * HD;
  const float* Kb = K + (size_t)bh * NN * HD;
  const float* Vb = V + (size_t)bh * NN * HD;

  // stage Q tile transposed and pre-scaled by 1/sqrt(64)
#pragma unroll
  for (int l = 0; l < 4; l++) {
    int fid = tid + l * 256;
    int row = fid >> 4, c4 = (fid & 15) << 2;
    float4 v = *reinterpret_cast<const float4*>(&Qb[(size_t)(qt * 64 + row) * HD + c4]);
    Qs[c4 + 0][row] = v.x * 0.125f;
    Qs[c4 + 1][row] = v.y * 0.125f;
    Qs[c4 + 2][row] = v.z * 0.125f;
    Qs[c4 + 3][row] = v.w * 0.125f;
  }

  float m_run[4], l_run[4], o[4][4];
#pragma unroll
  for (int i = 0; i < 4; i++) {
    m_run[i] = -INFINITY;
    l_run[i] = 0.f;
#pragma unroll
    for (int j = 0; j < 4; j++) o[i][j] = 0.f;
  }
  __syncthreads();

  for (int kt = 0; kt < NN / 64; kt++) {
    // stage K (transposed) and V (direct)
#pragma unroll
    for (int l = 0; l < 4; l++) {
      int fid = tid + l * 256;
      int row = fid >> 4, c4 = (fid & 15) << 2;
      float4 kv = *reinterpret_cast<const float4*>(&Kb[(size_t)(kt * 64 + row) * HD + c4]);
      KPs[c4 + 0][row] = kv.x;
      KPs[c4 + 1][row] = kv.y;
      KPs[c4 + 2][row] = kv.z;
      KPs[c4 + 3][row] = kv.w;
      *reinterpret_cast<float4*>(&Vs[row][c4]) =
          *reinterpret_cast<const float4*>(&Vb[(size_t)(kt * 64 + row) * HD + c4]);
    }
    __syncthreads();

    // S = (Q*scale) @ K^T for this tile: acc[i][j], rows ty*4+i, cols tx*4+j
    float acc[4][4];
#pragma unroll
    for (int i = 0; i < 4; i++)
#pragma unroll
      for (int j = 0; j < 4; j++) acc[i][j] = 0.f;
#pragma unroll
    for (int d = 0; d < 64; d++) {
      float4 a = *reinterpret_cast<const float4*>(&Qs[d][ty * 4]);
      float4 bv = *reinterpret_cast<const float4*>(&KPs[d][tx * 4]);
      float av[4] = {a.x, a.y, a.z, a.w};
      float bw[4] = {bv.x, bv.y, bv.z, bv.w};
#pragma unroll
      for (int i = 0; i < 4; i++)
#pragma unroll
        for (int j = 0; j < 4; j++) acc[i][j] = fmaf(av[i], bw[j], acc[i][j]);
    }

    // online softmax update (row state replicated across the 16-lane group)
    float pv[4][4];
#pragma unroll
    for (int i = 0; i < 4; i++) {
      float mt = fmaxf(fmaxf(acc[i][0], acc[i][1]), fmaxf(acc[i][2], acc[i][3]));
#pragma unroll
      for (int off = 1; off < 16; off <<= 1) mt = fmaxf(mt, __shfl_xor(mt, off, 64));
      float mn = fmaxf(m_run[i], mt);
      float corr = __expf(m_run[i] - mn);
      m_run[i] = mn;
      float rs = 0.f;
#pragma unroll
      for (int j = 0; j < 4; j++) {
        pv[i][j] = __expf(acc[i][j] - mn);
        rs += pv[i][j];
      }
#pragma unroll
      for (int off = 1; off < 16; off <<= 1) rs += __shfl_xor(rs, off, 64);
      l_run[i] = l_run[i] * corr + rs;
#pragma unroll
      for (int j = 0; j < 4; j++) o[i][j] *= corr;
    }

    __syncthreads();  // everyone done reading K from KPs
    // write P transposed: KPs[kc][r]
#pragma unroll
    for (int i = 0; i < 4; i++)
#pragma unroll
      for (int j = 0; j < 4; j++) KPs[tx * 4 + j][ty * 4 + i] = pv[i][j];
    __syncthreads();

    // O += P @ V : rows ty*4+i, d-cols tx*4+j
#pragma unroll
    for (int kc = 0; kc < 64; kc++) {
      float4 p = *reinterpret_cast<const float4*>(&KPs[kc][ty * 4]);
      float4 vv = *reinterpret_cast<const float4*>(&Vs[kc][tx * 4]);
      float pw[4] = {p.x, p.y, p.z, p.w};
      float vw[4] = {vv.x, vv.y, vv.z, vv.w};
#pragma unroll
      for (int i = 0; i < 4; i++)
#pragma unroll
        for (int j = 0; j < 4; j++) o[i][j] = fmaf(pw[i], vw[j], o[i][j]);
    }
    __syncthreads();  // before next tile overwrites KPs/Vs
  }

  // epilogue: normalize and write [B][N][C] with col = h*64 + d
#pragma unroll
  for (int i = 0; i < 4; i++) {
    float inv = 1.0f / l_run[i];
    int n = qt * 64 + ty * 4 + i;
    float4 v = make_float4(o[i][0] * inv, o[i][1] * inv, o[i][2] * inv, o[i][3] * inv);
    *reinterpret_cast<float4*>(&Out[((size_t)(b * NN + n) * CC) + h * HD + tx * 4]) = v;
  }
}

// ---------------- launch ----------------
extern "C" void kernel_launch(void* const* d_in, const int* in_sizes, int n_in,
                              void* d_out, int out_size, void* d_ws, size_t ws_size,
                              hipStream_t stream) {
  const float* x = (const float*)d_in[0];
  const float* Wqkv = (const float*)d_in[1];
  const float* Wout = (const float*)d_in[2];
  const float* cos_t = (const float*)d_in[3];
  const float* sin_t = (const float*)d_in[4];
  const float* cos_h = (const float*)d_in[5];
  const float* sin_h = (const float*)d_in[6];
  const float* cos_w = (const float*)d_in[7];
  const float* sin_w = (const float*)d_in[8];
  const int* t_idx = (const int*)d_in[9];
  const int* h_idx = (const int*)d_in[10];
  const int* w_idx = (const int*)d_in[11];
  float* out = (float*)d_out;

  float* ws = (float*)d_ws;
  float* qkv = ws;                        // 4096*2304 = 9437184 floats
  float* Qb = qkv + (size_t)4096 * 2304;  // 3145728 floats each
  float* Kb = Qb + (size_t)24 * 2048 * 64;
  float* Vb = Kb + (size_t)24 * 2048 * 64;
  float* attn = Vb + (size_t)24 * 2048 * 64;

  // qkv = x @ Wqkv   (4096 x 2304, K=768)
  sgemm_kernel<<<dim3(C3 / GBN, 4096 / GBM), 256, 0, stream>>>(x, Wqkv, qkv, 4096, C3, CC);
  // RoPE + scatter into head-major Q,K,V
  rope_kernel<<<dim3(BB * NN), 256, 0, stream>>>(qkv, cos_t, sin_t, cos_h, sin_h, cos_w,
                                                 sin_w, t_idx, h_idx, w_idx, Qb, Kb, Vb);
  // flash attention
  attn_kernel<<<dim3(NN / 64, BB * NHEAD), 256, 0, stream>>>(Qb, Kb, Vb, attn);
  // out = attn @ Wout  (4096 x 768, K=768)
  sgemm_kernel<<<dim3(CC / GBN, 4096 / GBM), 256, 0, stream>>>(attn, Wout, out, 4096, CC, CC);
}

// Round 2
// 470.398 us; speedup vs baseline: 1.6775x; 1.6775x over previous
//
#include <hip/hip_runtime.h>
#include <hip/hip_bf16.h>
#include <math.h>

// Problem constants
#define BB 2
#define NN 2048
#define CC 768
#define NHEAD 12
#define HD 64
#define C3 2304

typedef __attribute__((ext_vector_type(8))) short short8;
typedef __attribute__((ext_vector_type(4))) float f32x4;
#define MFMA16(a, b, c) __builtin_amdgcn_mfma_f32_16x16x32_bf16(a, b, c, 0, 0, 0)

__device__ __forceinline__ ushort f2bf(float x) {
  unsigned u = __builtin_bit_cast(unsigned, x);
  u += 0x7fffu + ((u >> 16) & 1u);
  return (ushort)(u >> 16);
}
__device__ __forceinline__ float bf2f(ushort h) {
  return __builtin_bit_cast(float, (unsigned)h << 16);
}

// ---------------- fp32 tiled GEMM: C = A @ B ----------------
constexpr int GBM = 128, GBN = 128, GBK = 16;

__global__ __launch_bounds__(256) void sgemm_kernel(const float* __restrict__ A,
                                                    const float* __restrict__ B,
                                                    float* __restrict__ C,
                                                    int M, int Nn, int K) {
  __shared__ float As[GBK][GBM + 4];
  __shared__ float Bs[GBK][GBN + 4];
  const int tid = threadIdx.x;
  const int tx = tid & 15, ty = tid >> 4;
  const int m0 = blockIdx.y * GBM, n0 = blockIdx.x * GBN;

  float acc[8][8];
#pragma unroll
  for (int i = 0; i < 8; i++)
#pragma unroll
    for (int j = 0; j < 8; j++) acc[i][j] = 0.f;

  for (int k0 = 0; k0 < K; k0 += GBK) {
#pragma unroll
    for (int l = 0; l < 2; l++) {
      int fid = tid + l * 256;
      int row = fid >> 2, c4 = (fid & 3) << 2;
      float4 v = *reinterpret_cast<const float4*>(&A[(size_t)(m0 + row) * K + k0 + c4]);
      As[c4 + 0][row] = v.x;
      As[c4 + 1][row] = v.y;
      As[c4 + 2][row] = v.z;
      As[c4 + 3][row] = v.w;
    }
#pragma unroll
    for (int l = 0; l < 2; l++) {
      int fid = tid + l * 256;
      int row = fid >> 5, c4 = (fid & 31) << 2;
      *reinterpret_cast<float4*>(&Bs[row][c4]) =
          *reinterpret_cast<const float4*>(&B[(size_t)(k0 + row) * Nn + n0 + c4]);
    }
    __syncthreads();

#pragma unroll
    for (int kk = 0; kk < GBK; kk++) {
      float4 a0 = *reinterpret_cast<const float4*>(&As[kk][ty * 4]);
      float4 a1 = *reinterpret_cast<const float4*>(&As[kk][64 + ty * 4]);
      float4 b0 = *reinterpret_cast<const float4*>(&Bs[kk][tx * 4]);
      float4 b1 = *reinterpret_cast<const float4*>(&Bs[kk][64 + tx * 4]);
      float av[8] = {a0.x, a0.y, a0.z, a0.w, a1.x, a1.y, a1.z, a1.w};
      float bv[8] = {b0.x, b0.y, b0.z, b0.w, b1.x, b1.y, b1.z, b1.w};
#pragma unroll
      for (int i = 0; i < 8; i++)
#pragma unroll
        for (int j = 0; j < 8; j++) acc[i][j] = fmaf(av[i], bv[j], acc[i][j]);
    }
    __syncthreads();
  }

#pragma unroll
  for (int bi = 0; bi < 2; bi++)
#pragma unroll
    for (int i = 0; i < 4; i++) {
      int r = m0 + bi * 64 + ty * 4 + i;
#pragma unroll
      for (int bj = 0; bj < 2; bj++) {
        float4 v = make_float4(acc[bi * 4 + i][bj * 4 + 0], acc[bi * 4 + i][bj * 4 + 1],
                               acc[bi * 4 + i][bj * 4 + 2], acc[bi * 4 + i][bj * 4 + 3]);
        *reinterpret_cast<float4*>(&C[(size_t)r * Nn + n0 + bj * 64 + tx * 4]) = v;
      }
    }
}

// ---------------- RoPE + bf16 hi/lo split + head-major scatter ----------------
// qkv: [B*N][2304] fp32. Writes Qhi/Qlo/Khi/Klo [bh][n][64] bf16 (Q pre-scaled
// by 1/8), V transposed Vt [bh][d][n] bf16.
__global__ __launch_bounds__(256) void rope_split_kernel(
    const float* __restrict__ qkv, const float* __restrict__ cos_t,
    const float* __restrict__ sin_t, const float* __restrict__ cos_h,
    const float* __restrict__ sin_h, const float* __restrict__ cos_w,
    const float* __restrict__ sin_w, const int* __restrict__ t_idx,
    const int* __restrict__ h_idx, const int* __restrict__ w_idx,
    ushort* __restrict__ Qhi, ushort* __restrict__ Qlo, ushort* __restrict__ Khi,
    ushort* __restrict__ Klo, ushort* __restrict__ Vt) {
  const int tok = blockIdx.x;  // 0..B*N-1
  const int b = tok >> 11, n = tok & 2047;
  const int ti = t_idx[n], hi = h_idx[n], wi = w_idx[n];
  const float* base = qkv + (size_t)tok * C3;

#pragma unroll
  for (int s = 0; s < 3; s++) {
    int j = threadIdx.x + s * 256;
    float c, sn, sign;
    int pj;
    if (j < 192) {
      int jj = j;
      c = cos_t[ti * 192 + jj];
      sn = sin_t[ti * 192 + jj];
      pj = (jj < 96) ? j + 96 : j - 96;
      sign = (jj < 96) ? -1.f : 1.f;
    } else if (j < 480) {
      int jj = j - 192;
      c = cos_h[hi * 288 + jj];
      sn = sin_h[hi * 288 + jj];
      pj = (jj < 144) ? j + 144 : j - 144;
      sign = (jj < 144) ? -1.f : 1.f;
    } else {
      int jj = j - 480;
      c = cos_w[wi * 288 + jj];
      sn = sin_w[wi * 288 + jj];
      pj = (jj < 144) ? j + 144 : j - 144;
      sign = (jj < 144) ? -1.f : 1.f;
    }
    float qv = base[j], kv = base[768 + j], vv = base[1536 + j];
    float qp = base[pj] * sign, kp = base[768 + pj] * sign;
    float qr = fmaf(qv, c, qp * sn) * 0.125f;  // pre-scale by 1/sqrt(64)
    float kr = fmaf(kv, c, kp * sn);
    int h = j >> 6, d = j & 63;
    int bh = b * NHEAD + h;
    size_t o = ((size_t)bh * NN + n) * HD + d;
    ushort qh = f2bf(qr);
    Qhi[o] = qh;
    Qlo[o] = f2bf(qr - bf2f(qh));
    ushort kh = f2bf(kr);
    Khi[o] = kh;
    Klo[o] = f2bf(kr - bf2f(kh));
    Vt[((size_t)bh * HD + d) * NN + n] = f2bf(vv);
  }
}

// ---------------- bf16 MFMA flash attention ----------------
// Qhi/Qlo/Khi/Klo: [bh][n][64] bf16; Vt: [bh][d][n] bf16. Out: [B][N][C] fp32.
// 256 thr = 4 waves; wave w owns q-rows [qt*64+w*16, +16). K-tile = 64.
// S = Qhi*Khi + Qhi*Klo + Qlo*Khi (split-bf16, ~fp32-accurate), PV plain bf16.
__global__ __launch_bounds__(256) void attn_mfma_kernel(
    const ushort* __restrict__ Qhi, const ushort* __restrict__ Qlo,
    const ushort* __restrict__ Khi, const ushort* __restrict__ Klo,
    const ushort* __restrict__ Vt, float* __restrict__ Out) {
  __shared__ __align__(16) ushort Kh[64][72];
  __shared__ __align__(16) ushort Kl[64][72];
  __shared__ __align__(16) ushort Vs[64][72];  // [d][k-local]
  __shared__ __align__(16) ushort Ps[64][72];  // [q-local][k-local]
  const int tid = threadIdx.x;
  const int lane = tid & 63, w = tid >> 6;
  const int l15 = lane & 15, lg = lane >> 4;
  const int qt = blockIdx.x;  // 0..31
  const int bh = blockIdx.y;  // 0..23
  const int b = bh / NHEAD, h = bh % NHEAD;
  const size_t base = (size_t)bh * NN * HD;

  // persistent Q fragments (A-layout: row = lane&15, k-chunk = (lane>>4)*8)
  short8 qh[2], ql[2];
  {
    const int r = qt * 64 + w * 16 + l15;
    const ushort* qrowh = Qhi + base + (size_t)r * HD;
    const ushort* qrowl = Qlo + base + (size_t)r * HD;
#pragma unroll
    for (int s = 0; s < 2; s++) {
      qh[s] = *reinterpret_cast<const short8*>(qrowh + s * 32 + lg * 8);
      ql[s] = *reinterpret_cast<const short8*>(qrowl + s * 32 + lg * 8);
    }
  }

  f32x4 o_acc[4];
  float m_run[4], l_run[4];
#pragma unroll
  for (int g = 0; g < 4; g++) o_acc[g] = (f32x4){0.f, 0.f, 0.f, 0.f};
#pragma unroll
  for (int j = 0; j < 4; j++) {
    m_run[j] = -INFINITY;
    l_run[j] = 0.f;
  }

  for (int kt = 0; kt < NN / 64; kt++) {
    // ---- stage K hi/lo (row-major [k][d]) and V (Vt rows → [d][k-local]) ----
#pragma unroll
    for (int i = 0; i < 2; i++) {
      int row = (tid >> 3) + i * 32;
      int d0 = (tid & 7) * 8;
      const ushort* kh_src = Khi + base + (size_t)(kt * 64 + row) * HD + d0;
      const ushort* kl_src = Klo + base + (size_t)(kt * 64 + row) * HD + d0;
      const ushort* v_src = Vt + ((size_t)bh * HD + row) * NN + kt * 64 + d0;
      *reinterpret_cast<int4*>(&Kh[row][d0]) = *reinterpret_cast<const int4*>(kh_src);
      *reinterpret_cast<int4*>(&Kl[row][d0]) = *reinterpret_cast<const int4*>(kl_src);
      *reinterpret_cast<int4*>(&Vs[row][d0]) = *reinterpret_cast<const int4*>(v_src);
    }
    __syncthreads();

    // ---- S = Q K^T (split bf16) ----
    f32x4 s_acc[4];
#pragma unroll
    for (int g = 0; g < 4; g++) s_acc[g] = (f32x4){0.f, 0.f, 0.f, 0.f};
#pragma unroll
    for (int g = 0; g < 4; g++) {
#pragma unroll
      for (int s = 0; s < 2; s++) {
        short8 kbh = *reinterpret_cast<const short8*>(&Kh[g * 16 + l15][s * 32 + lg * 8]);
        short8 kbl = *reinterpret_cast<const short8*>(&Kl[g * 16 + l15][s * 32 + lg * 8]);
        s_acc[g] = MFMA16(qh[s], kbh, s_acc[g]);
        s_acc[g] = MFMA16(qh[s], kbl, s_acc[g]);
        s_acc[g] = MFMA16(ql[s], kbh, s_acc[g]);
      }
    }

    // ---- online softmax (rows = lg*4+j, cols = g*16+l15) ----
    float corr[4];
#pragma unroll
    for (int j = 0; j < 4; j++) {
      float mt = fmaxf(fmaxf(s_acc[0][j], s_acc[1][j]), fmaxf(s_acc[2][j], s_acc[3][j]));
#pragma unroll
      for (int off = 1; off < 16; off <<= 1) mt = fmaxf(mt, __shfl_xor(mt, off, 64));
      float mn = fmaxf(m_run[j], mt);
      corr[j] = __expf(m_run[j] - mn);
      m_run[j] = mn;
      float rs = 0.f;
      float p[4];
#pragma unroll
      for (int g = 0; g < 4; g++) {
        p[g] = __expf(s_acc[g][j] - mn);
        rs += p[g];
      }
#pragma unroll
      for (int off = 1; off < 16; off <<= 1) rs += __shfl_xor(rs, off, 64);
      l_run[j] = l_run[j] * corr[j] + rs;
#pragma unroll
      for (int g = 0; g < 4; g++) Ps[w * 16 + lg * 4 + j][g * 16 + l15] = f2bf(p[g]);
    }

    // rescale O
#pragma unroll
    for (int g = 0; g < 4; g++)
#pragma unroll
      for (int j = 0; j < 4; j++) o_acc[g][j] *= corr[j];

    // ---- O += P @ V ----
#pragma unroll
    for (int kk = 0; kk < 2; kk++) {
      short8 pa = *reinterpret_cast<const short8*>(&Ps[w * 16 + l15][kk * 32 + lg * 8]);
#pragma unroll
      for (int g = 0; g < 4; g++) {
        short8 vb = *reinterpret_cast<const short8*>(&Vs[g * 16 + l15][kk * 32 + lg * 8]);
        o_acc[g] = MFMA16(pa, vb, o_acc[g]);
      }
    }
    __syncthreads();
  }

  // ---- epilogue: normalize, write [B][N][C] ----
#pragma unroll
  for (int j = 0; j < 4; j++) {
    float inv = 1.0f / l_run[j];
    int n = qt * 64 + w * 16 + lg * 4 + j;
#pragma unroll
    for (int g = 0; g < 4; g++)
      Out[(size_t)(b * NN + n) * CC + h * 64 + g * 16 + l15] = o_acc[g][j] * inv;
  }
}

// ---------------- launch ----------------
extern "C" void kernel_launch(void* const* d_in, const int* in_sizes, int n_in,
                              void* d_out, int out_size, void* d_ws, size_t ws_size,
                              hipStream_t stream) {
  const float* x = (const float*)d_in[0];
  const float* Wqkv = (const float*)d_in[1];
  const float* Wout = (const float*)d_in[2];
  const float* cos_t = (const float*)d_in[3];
  const float* sin_t = (const float*)d_in[4];
  const float* cos_h = (const float*)d_in[5];
  const float* sin_h = (const float*)d_in[6];
  const float* cos_w = (const float*)d_in[7];
  const float* sin_w = (const float*)d_in[8];
  const int* t_idx = (const int*)d_in[9];
  const int* h_idx = (const int*)d_in[10];
  const int* w_idx = (const int*)d_in[11];
  float* out = (float*)d_out;

  float* ws = (float*)d_ws;
  float* qkv = ws;                          // 4096*2304 fp32
  float* attn = qkv + (size_t)4096 * 2304;  // 4096*768 fp32
  ushort* us = (ushort*)(attn + (size_t)4096 * 768);
  const size_t HS = (size_t)24 * 2048 * 64;  // 3,145,728 elements
  ushort* Qhi = us;
  ushort* Qlo = Qhi + HS;
  ushort* Khi = Qlo + HS;
  ushort* Klo = Khi + HS;
  ushort* Vt = Klo + HS;

  // qkv = x @ Wqkv
  sgemm_kernel<<<dim3(C3 / GBN, 4096 / GBM), 256, 0, stream>>>(x, Wqkv, qkv, 4096, C3, CC);
  // RoPE + bf16 split + scatter
  rope_split_kernel<<<dim3(BB * NN), 256, 0, stream>>>(qkv, cos_t, sin_t, cos_h, sin_h,
                                                       cos_w, sin_w, t_idx, h_idx, w_idx,
                                                       Qhi, Qlo, Khi, Klo, Vt);
  // flash attention (bf16 MFMA)
  attn_mfma_kernel<<<dim3(NN / 64, BB * NHEAD), 256, 0, stream>>>(Qhi, Qlo, Khi, Klo, Vt,
                                                                  attn);
  // out = attn @ Wout
  sgemm_kernel<<<dim3(CC / GBN, 4096 / GBM), 256, 0, stream>>>(attn, Wout, out, 4096, CC, CC);
}

// Round 3
// 265.559 us; speedup vs baseline: 2.9714x; 1.7713x over previous
//
#include <hip/hip_runtime.h>
#include <hip/hip_bf16.h>
#include <math.h>

// Problem constants
#define BB 2
#define NN 2048
#define CC 768
#define NHEAD 12
#define HD 64
#define C3 2304

typedef __attribute__((ext_vector_type(8))) short short8;
typedef __attribute__((ext_vector_type(4))) float f32x4;
#define MFMA16(a, b, c) __builtin_amdgcn_mfma_f32_16x16x32_bf16(a, b, c, 0, 0, 0)

__device__ __forceinline__ ushort f2bf(float x) {
  unsigned u = __builtin_bit_cast(unsigned, x);
  u += 0x7fffu + ((u >> 16) & 1u);
  return (ushort)(u >> 16);
}
__device__ __forceinline__ float bf2f(ushort h) {
  return __builtin_bit_cast(float, (unsigned)h << 16);
}

__device__ __forceinline__ void gload_lds16(const void* gsrc, void* lds) {
  __builtin_amdgcn_global_load_lds(
      (const __attribute__((address_space(1))) unsigned int*)gsrc,
      (__attribute__((address_space(3))) unsigned int*)lds, 16, 0, 0);
}

// ---------------- input split kernels ----------------
// X: [4096][768] fp32 -> Xs: [4096][2][768] bf16 (hi row, lo row interleaved)
__global__ __launch_bounds__(256) void split_rows_kernel(const float* __restrict__ X,
                                                         ushort* __restrict__ Xs) {
  int idx = blockIdx.x * 256 + threadIdx.x;  // 4096*192 total
  int m = idx / 192, c4 = (idx % 192) * 4;
  float4 v = *reinterpret_cast<const float4*>(&X[(size_t)m * 768 + c4]);
  float vals[4] = {v.x, v.y, v.z, v.w};
  ushort hs[4], ls[4];
#pragma unroll
  for (int i = 0; i < 4; i++) {
    hs[i] = f2bf(vals[i]);
    ls[i] = f2bf(vals[i] - bf2f(hs[i]));
  }
  size_t o = (size_t)m * 1536 + c4;
  *reinterpret_cast<ushort4*>(&Xs[o]) = make_ushort4(hs[0], hs[1], hs[2], hs[3]);
  *reinterpret_cast<ushort4*>(&Xs[o + 768]) = make_ushort4(ls[0], ls[1], ls[2], ls[3]);
}

// W: [768][N] fp32 -> Ws: [N][2][768] bf16 (transposed + split)
__global__ __launch_bounds__(256) void split_transpose_kernel(const float* __restrict__ W,
                                                              ushort* __restrict__ Ws,
                                                              int N) {
  __shared__ float t[32][33];
  const int tx = threadIdx.x & 31, ty = threadIdx.x >> 5;  // 32 x 8
  const int n0 = blockIdx.x * 32, k0 = blockIdx.y * 32;
#pragma unroll
  for (int r = 0; r < 4; r++) {
    int kk = ty + r * 8;
    t[kk][tx] = W[(size_t)(k0 + kk) * N + n0 + tx];
  }
  __syncthreads();
#pragma unroll
  for (int r = 0; r < 4; r++) {
    int nn = ty + r * 8;
    float v = t[tx][nn];
    ushort hi = f2bf(v);
    ushort lo = f2bf(v - bf2f(hi));
    size_t o = (size_t)(n0 + nn) * 1536 + k0 + tx;
    Ws[o] = hi;
    Ws[o + 768] = lo;
  }
}

// ---------------- split-bf16 MFMA GEMM ----------------
// A: [M][2][768] bf16 hi/lo, B: [N][2][768] bf16 hi/lo (pre-transposed),
// C: [M][N] fp32 = A@B (3-term split: hi*hi + hi*lo + lo*hi).
// 128x128 tile, BK=32, 4 waves. LDS rows = 128B (32 hi k + 32 lo k) with
// chunk ^= (row&7) XOR swizzle applied via pre-swizzled global source.
__global__ __launch_bounds__(256) void gemm_split_kernel(const ushort* __restrict__ A,
                                                         const ushort* __restrict__ B,
                                                         float* __restrict__ C, int Nn) {
  __shared__ __align__(16) ushort Asm[128 * 64];
  __shared__ __align__(16) ushort Bsm[128 * 64];
  const int tid = threadIdx.x;
  const int lane = tid & 63, w = tid >> 6;
  const int l15 = lane & 15, lg = lane >> 4;
  const int wr = w >> 1, wc = w & 1;
  const int m0 = blockIdx.y * 128, n0 = blockIdx.x * 128;
  const int lrow = lane >> 3, lc = lane & 7;

  f32x4 acc[4][4];
#pragma unroll
  for (int m = 0; m < 4; m++)
#pragma unroll
    for (int n = 0; n < 4; n++) acc[m][n] = (f32x4){0.f, 0.f, 0.f, 0.f};

  for (int k0 = 0; k0 < 768; k0 += 32) {
    // stage: each wave stages 8 rows per iteration x 4 iterations, A and B
#pragma unroll
    for (int it = 0; it < 4; it++) {
      int r0 = it * 32 + w * 8;
      int row = r0 + lrow;
      int cp = lc ^ (row & 7);  // chunk stored at position lc is logical cp
      size_t goff = (size_t)row * 1536 + (cp >> 2) * 768 + k0 + (cp & 3) * 8;
      gload_lds16(A + (size_t)m0 * 1536 + goff, &Asm[r0 * 64]);
      gload_lds16(B + (size_t)n0 * 1536 + goff, &Bsm[r0 * 64]);
    }
    __syncthreads();

    short8 ah[4], al[4], bh[4], bl[4];
#pragma unroll
    for (int m = 0; m < 4; m++) {
      int row = wr * 64 + m * 16 + l15;
      int cpos = lg ^ (row & 7);
      ah[m] = *reinterpret_cast<const short8*>(&Asm[row * 64 + cpos * 8]);
      al[m] = *reinterpret_cast<const short8*>(&Asm[row * 64 + (cpos ^ 4) * 8]);
    }
#pragma unroll
    for (int n = 0; n < 4; n++) {
      int col = wc * 64 + n * 16 + l15;
      int cpos = lg ^ (col & 7);
      bh[n] = *reinterpret_cast<const short8*>(&Bsm[col * 64 + cpos * 8]);
      bl[n] = *reinterpret_cast<const short8*>(&Bsm[col * 64 + (cpos ^ 4) * 8]);
    }
#pragma unroll
    for (int m = 0; m < 4; m++)
#pragma unroll
      for (int n = 0; n < 4; n++) {
        acc[m][n] = MFMA16(ah[m], bh[n], acc[m][n]);
        acc[m][n] = MFMA16(ah[m], bl[n], acc[m][n]);
        acc[m][n] = MFMA16(al[m], bh[n], acc[m][n]);
      }
    __syncthreads();
  }

#pragma unroll
  for (int m = 0; m < 4; m++)
#pragma unroll
    for (int j = 0; j < 4; j++) {
      int row = m0 + wr * 64 + m * 16 + lg * 4 + j;
#pragma unroll
      for (int n = 0; n < 4; n++)
        C[(size_t)row * Nn + n0 + wc * 64 + n * 16 + l15] = acc[m][n][j];
    }
}

// ---------------- RoPE + bf16 hi/lo split + head-major scatter ----------------
__global__ __launch_bounds__(256) void rope_split_kernel(
    const float* __restrict__ qkv, const float* __restrict__ cos_t,
    const float* __restrict__ sin_t, const float* __restrict__ cos_h,
    const float* __restrict__ sin_h, const float* __restrict__ cos_w,
    const float* __restrict__ sin_w, const int* __restrict__ t_idx,
    const int* __restrict__ h_idx, const int* __restrict__ w_idx,
    ushort* __restrict__ Qhi, ushort* __restrict__ Qlo, ushort* __restrict__ Khi,
    ushort* __restrict__ Klo, ushort* __restrict__ Vt) {
  const int tok = blockIdx.x;  // 0..B*N-1
  const int b = tok >> 11, n = tok & 2047;
  const int ti = t_idx[n], hi = h_idx[n], wi = w_idx[n];
  const float* base = qkv + (size_t)tok * C3;

#pragma unroll
  for (int s = 0; s < 3; s++) {
    int j = threadIdx.x + s * 256;
    float c, sn, sign;
    int pj;
    if (j < 192) {
      int jj = j;
      c = cos_t[ti * 192 + jj];
      sn = sin_t[ti * 192 + jj];
      pj = (jj < 96) ? j + 96 : j - 96;
      sign = (jj < 96) ? -1.f : 1.f;
    } else if (j < 480) {
      int jj = j - 192;
      c = cos_h[hi * 288 + jj];
      sn = sin_h[hi * 288 + jj];
      pj = (jj < 144) ? j + 144 : j - 144;
      sign = (jj < 144) ? -1.f : 1.f;
    } else {
      int jj = j - 480;
      c = cos_w[wi * 288 + jj];
      sn = sin_w[wi * 288 + jj];
      pj = (jj < 144) ? j + 144 : j - 144;
      sign = (jj < 144) ? -1.f : 1.f;
    }
    float qv = base[j], kv = base[768 + j], vv = base[1536 + j];
    float qp = base[pj] * sign, kp = base[768 + pj] * sign;
    float qr = fmaf(qv, c, qp * sn) * 0.125f;  // pre-scale by 1/sqrt(64)
    float kr = fmaf(kv, c, kp * sn);
    int h = j >> 6, d = j & 63;
    int bh = b * NHEAD + h;
    size_t o = ((size_t)bh * NN + n) * HD + d;
    ushort qh = f2bf(qr);
    Qhi[o] = qh;
    Qlo[o] = f2bf(qr - bf2f(qh));
    ushort kh = f2bf(kr);
    Khi[o] = kh;
    Klo[o] = f2bf(kr - bf2f(kh));
    Vt[((size_t)bh * HD + d) * NN + n] = f2bf(vv);
  }
}

// ---------------- bf16 MFMA flash attention ----------------
// Epilogue writes AttnS: [B*N][2][768] bf16 hi/lo (A-operand of out-proj GEMM).
__global__ __launch_bounds__(256) void attn_mfma_kernel(
    const ushort* __restrict__ Qhi, const ushort* __restrict__ Qlo,
    const ushort* __restrict__ Khi, const ushort* __restrict__ Klo,
    const ushort* __restrict__ Vt, ushort* __restrict__ AttnS) {
  __shared__ __align__(16) ushort Kh[64][72];
  __shared__ __align__(16) ushort Kl[64][72];
  __shared__ __align__(16) ushort Vs[64][72];  // [d][k-local]
  __shared__ __align__(16) ushort Ps[64][72];  // [q-local][k-local]
  const int tid = threadIdx.x;
  const int lane = tid & 63, w = tid >> 6;
  const int l15 = lane & 15, lg = lane >> 4;
  const int qt = blockIdx.x;  // 0..31
  const int bh = blockIdx.y;  // 0..23
  const int b = bh / NHEAD, h = bh % NHEAD;
  const size_t base = (size_t)bh * NN * HD;

  short8 qh[2], ql[2];
  {
    const int r = qt * 64 + w * 16 + l15;
    const ushort* qrowh = Qhi + base + (size_t)r * HD;
    const ushort* qrowl = Qlo + base + (size_t)r * HD;
#pragma unroll
    for (int s = 0; s < 2; s++) {
      qh[s] = *reinterpret_cast<const short8*>(qrowh + s * 32 + lg * 8);
      ql[s] = *reinterpret_cast<const short8*>(qrowl + s * 32 + lg * 8);
    }
  }

  f32x4 o_acc[4];
  float m_run[4], l_run[4];
#pragma unroll
  for (int g = 0; g < 4; g++) o_acc[g] = (f32x4){0.f, 0.f, 0.f, 0.f};
#pragma unroll
  for (int j = 0; j < 4; j++) {
    m_run[j] = -INFINITY;
    l_run[j] = 0.f;
  }

  for (int kt = 0; kt < NN / 64; kt++) {
#pragma unroll
    for (int i = 0; i < 2; i++) {
      int row = (tid >> 3) + i * 32;
      int d0 = (tid & 7) * 8;
      const ushort* kh_src = Khi + base + (size_t)(kt * 64 + row) * HD + d0;
      const ushort* kl_src = Klo + base + (size_t)(kt * 64 + row) * HD + d0;
      const ushort* v_src = Vt + ((size_t)bh * HD + row) * NN + kt * 64 + d0;
      *reinterpret_cast<int4*>(&Kh[row][d0]) = *reinterpret_cast<const int4*>(kh_src);
      *reinterpret_cast<int4*>(&Kl[row][d0]) = *reinterpret_cast<const int4*>(kl_src);
      *reinterpret_cast<int4*>(&Vs[row][d0]) = *reinterpret_cast<const int4*>(v_src);
    }
    __syncthreads();

    f32x4 s_acc[4];
#pragma unroll
    for (int g = 0; g < 4; g++) s_acc[g] = (f32x4){0.f, 0.f, 0.f, 0.f};
#pragma unroll
    for (int g = 0; g < 4; g++) {
#pragma unroll
      for (int s = 0; s < 2; s++) {
        short8 kbh = *reinterpret_cast<const short8*>(&Kh[g * 16 + l15][s * 32 + lg * 8]);
        short8 kbl = *reinterpret_cast<const short8*>(&Kl[g * 16 + l15][s * 32 + lg * 8]);
        s_acc[g] = MFMA16(qh[s], kbh, s_acc[g]);
        s_acc[g] = MFMA16(qh[s], kbl, s_acc[g]);
        s_acc[g] = MFMA16(ql[s], kbh, s_acc[g]);
      }
    }

    float corr[4];
#pragma unroll
    for (int j = 0; j < 4; j++) {
      float mt = fmaxf(fmaxf(s_acc[0][j], s_acc[1][j]), fmaxf(s_acc[2][j], s_acc[3][j]));
#pragma unroll
      for (int off = 1; off < 16; off <<= 1) mt = fmaxf(mt, __shfl_xor(mt, off, 64));
      float mn = fmaxf(m_run[j], mt);
      corr[j] = __expf(m_run[j] - mn);
      m_run[j] = mn;
      float rs = 0.f;
      float p[4];
#pragma unroll
      for (int g = 0; g < 4; g++) {
        p[g] = __expf(s_acc[g][j] - mn);
        rs += p[g];
      }
#pragma unroll
      for (int off = 1; off < 16; off <<= 1) rs += __shfl_xor(rs, off, 64);
      l_run[j] = l_run[j] * corr[j] + rs;
#pragma unroll
      for (int g = 0; g < 4; g++) Ps[w * 16 + lg * 4 + j][g * 16 + l15] = f2bf(p[g]);
    }

#pragma unroll
    for (int g = 0; g < 4; g++)
#pragma unroll
      for (int j = 0; j < 4; j++) o_acc[g][j] *= corr[j];

#pragma unroll
    for (int kk = 0; kk < 2; kk++) {
      short8 pa = *reinterpret_cast<const short8*>(&Ps[w * 16 + l15][kk * 32 + lg * 8]);
#pragma unroll
      for (int g = 0; g < 4; g++) {
        short8 vb = *reinterpret_cast<const short8*>(&Vs[g * 16 + l15][kk * 32 + lg * 8]);
        o_acc[g] = MFMA16(pa, vb, o_acc[g]);
      }
    }
    __syncthreads();
  }

  // epilogue: normalize, split to bf16 hi/lo for the out-proj GEMM
#pragma unroll
  for (int j = 0; j < 4; j++) {
    float inv = 1.0f / l_run[j];
    int n = qt * 64 + w * 16 + lg * 4 + j;
    size_t rowbase = (size_t)(b * NN + n) * 1536;
#pragma unroll
    for (int g = 0; g < 4; g++) {
      float val = o_acc[g][j] * inv;
      ushort hi = f2bf(val);
      ushort lo = f2bf(val - bf2f(hi));
      int col = h * 64 + g * 16 + l15;
      AttnS[rowbase + col] = hi;
      AttnS[rowbase + 768 + col] = lo;
    }
  }
}

// ---------------- launch ----------------
extern "C" void kernel_launch(void* const* d_in, const int* in_sizes, int n_in,
                              void* d_out, int out_size, void* d_ws, size_t ws_size,
                              hipStream_t stream) {
  const float* x = (const float*)d_in[0];
  const float* Wqkv = (const float*)d_in[1];
  const float* Wout = (const float*)d_in[2];
  const float* cos_t = (const float*)d_in[3];
  const float* sin_t = (const float*)d_in[4];
  const float* cos_h = (const float*)d_in[5];
  const float* sin_h = (const float*)d_in[6];
  const float* cos_w = (const float*)d_in[7];
  const float* sin_w = (const float*)d_in[8];
  const int* t_idx = (const int*)d_in[9];
  const int* h_idx = (const int*)d_in[10];
  const int* w_idx = (const int*)d_in[11];
  float* out = (float*)d_out;

  float* ws = (float*)d_ws;
  float* qkv = ws;  // 4096*2304 fp32
  ushort* us = (ushort*)(qkv + (size_t)4096 * 2304);
  const size_t HS = (size_t)24 * 2048 * 64;
  ushort* Qhi = us;
  ushort* Qlo = Qhi + HS;
  ushort* Khi = Qlo + HS;
  ushort* Klo = Khi + HS;
  ushort* Vt = Klo + HS;
  ushort* xs = Vt + HS;                       // 4096*1536
  ushort* wqs = xs + (size_t)4096 * 1536;     // 2304*1536
  ushort* wos = wqs + (size_t)2304 * 1536;    // 768*1536
  ushort* attns = wos + (size_t)768 * 1536;   // 4096*1536

  // input conversions
  split_rows_kernel<<<dim3(4096 * 192 / 256), 256, 0, stream>>>(x, xs);
  split_transpose_kernel<<<dim3(C3 / 32, CC / 32), 256, 0, stream>>>(Wqkv, wqs, C3);
  split_transpose_kernel<<<dim3(CC / 32, CC / 32), 256, 0, stream>>>(Wout, wos, CC);
  // qkv = x @ Wqkv  (split-bf16 MFMA)
  gemm_split_kernel<<<dim3(C3 / 128, 4096 / 128), 256, 0, stream>>>(xs, wqs, qkv, C3);
  // RoPE + bf16 split + scatter
  rope_split_kernel<<<dim3(BB * NN), 256, 0, stream>>>(qkv, cos_t, sin_t, cos_h, sin_h,
                                                       cos_w, sin_w, t_idx, h_idx, w_idx,
                                                       Qhi, Qlo, Khi, Klo, Vt);
  // flash attention (bf16 MFMA), emits split bf16 directly
  attn_mfma_kernel<<<dim3(NN / 64, BB * NHEAD), 256, 0, stream>>>(Qhi, Qlo, Khi, Klo, Vt,
                                                                  attns);
  // out = attn @ Wout  (split-bf16 MFMA)
  gemm_split_kernel<<<dim3(CC / 128, 4096 / 128), 256, 0, stream>>>(attns, wos, out, CC);
}

// Round 4
// 213.485 us; speedup vs baseline: 3.6962x; 1.2439x over previous
//
#include <hip/hip_runtime.h>
#include <hip/hip_bf16.h>
#include <math.h>

// Problem constants
#define BB 2
#define NN 2048
#define CC 768
#define NHEAD 12
#define HD 64
#define C3 2304

typedef __attribute__((ext_vector_type(8))) short short8;
typedef __attribute__((ext_vector_type(4))) float f32x4;
typedef __attribute__((ext_vector_type(4))) unsigned uint4v;
#define MFMA16(a, b, c) __builtin_amdgcn_mfma_f32_16x16x32_bf16(a, b, c, 0, 0, 0)

__device__ __forceinline__ ushort f2bf(float x) {
  unsigned u = __builtin_bit_cast(unsigned, x);
  u += 0x7fffu + ((u >> 16) & 1u);
  return (ushort)(u >> 16);
}
__device__ __forceinline__ float bf2f(ushort h) {
  return __builtin_bit_cast(float, (unsigned)h << 16);
}
__device__ __forceinline__ unsigned cvt_pk_bf16(float lo, float hi) {
  unsigned r;
  asm("v_cvt_pk_bf16_f32 %0, %1, %2" : "=v"(r) : "v"(lo), "v"(hi));
  return r;
}

__device__ __forceinline__ void gload_lds16(const void* gsrc, void* lds) {
  __builtin_amdgcn_global_load_lds(
      (const __attribute__((address_space(1))) unsigned int*)gsrc,
      (__attribute__((address_space(3))) unsigned int*)lds, 16, 0, 0);
}

// ---------------- input split kernels ----------------
__global__ __launch_bounds__(256) void split_rows_kernel(const float* __restrict__ X,
                                                         ushort* __restrict__ Xs) {
  int idx = blockIdx.x * 256 + threadIdx.x;  // 4096*192 total
  int m = idx / 192, c4 = (idx % 192) * 4;
  float4 v = *reinterpret_cast<const float4*>(&X[(size_t)m * 768 + c4]);
  float vals[4] = {v.x, v.y, v.z, v.w};
  ushort hs[4], ls[4];
#pragma unroll
  for (int i = 0; i < 4; i++) {
    hs[i] = f2bf(vals[i]);
    ls[i] = f2bf(vals[i] - bf2f(hs[i]));
  }
  size_t o = (size_t)m * 1536 + c4;
  *reinterpret_cast<ushort4*>(&Xs[o]) = make_ushort4(hs[0], hs[1], hs[2], hs[3]);
  *reinterpret_cast<ushort4*>(&Xs[o + 768]) = make_ushort4(ls[0], ls[1], ls[2], ls[3]);
}

__global__ __launch_bounds__(256) void split_transpose_kernel(const float* __restrict__ W,
                                                              ushort* __restrict__ Ws,
                                                              int N) {
  __shared__ float t[32][33];
  const int tx = threadIdx.x & 31, ty = threadIdx.x >> 5;  // 32 x 8
  const int n0 = blockIdx.x * 32, k0 = blockIdx.y * 32;
#pragma unroll
  for (int r = 0; r < 4; r++) {
    int kk = ty + r * 8;
    t[kk][tx] = W[(size_t)(k0 + kk) * N + n0 + tx];
  }
  __syncthreads();
#pragma unroll
  for (int r = 0; r < 4; r++) {
    int nn = ty + r * 8;
    float v = t[tx][nn];
    ushort hi = f2bf(v);
    ushort lo = f2bf(v - bf2f(hi));
    size_t o = (size_t)(n0 + nn) * 1536 + k0 + tx;
    Ws[o] = hi;
    Ws[o + 768] = lo;
  }
}

// ---------------- split-bf16 MFMA GEMM (unchanged from R3) ----------------
__global__ __launch_bounds__(256) void gemm_split_kernel(const ushort* __restrict__ A,
                                                         const ushort* __restrict__ B,
                                                         float* __restrict__ C, int Nn) {
  __shared__ __align__(16) ushort Asm[128 * 64];
  __shared__ __align__(16) ushort Bsm[128 * 64];
  const int tid = threadIdx.x;
  const int lane = tid & 63, w = tid >> 6;
  const int l15 = lane & 15, lg = lane >> 4;
  const int wr = w >> 1, wc = w & 1;
  const int m0 = blockIdx.y * 128, n0 = blockIdx.x * 128;
  const int lrow = lane >> 3, lc = lane & 7;

  f32x4 acc[4][4];
#pragma unroll
  for (int m = 0; m < 4; m++)
#pragma unroll
    for (int n = 0; n < 4; n++) acc[m][n] = (f32x4){0.f, 0.f, 0.f, 0.f};

  for (int k0 = 0; k0 < 768; k0 += 32) {
#pragma unroll
    for (int it = 0; it < 4; it++) {
      int r0 = it * 32 + w * 8;
      int row = r0 + lrow;
      int cp = lc ^ (row & 7);
      size_t goff = (size_t)row * 1536 + (cp >> 2) * 768 + k0 + (cp & 3) * 8;
      gload_lds16(A + (size_t)m0 * 1536 + goff, &Asm[r0 * 64]);
      gload_lds16(B + (size_t)n0 * 1536 + goff, &Bsm[r0 * 64]);
    }
    __syncthreads();

    short8 ah[4], al[4], bh[4], bl[4];
#pragma unroll
    for (int m = 0; m < 4; m++) {
      int row = wr * 64 + m * 16 + l15;
      int cpos = lg ^ (row & 7);
      ah[m] = *reinterpret_cast<const short8*>(&Asm[row * 64 + cpos * 8]);
      al[m] = *reinterpret_cast<const short8*>(&Asm[row * 64 + (cpos ^ 4) * 8]);
    }
#pragma unroll
    for (int n = 0; n < 4; n++) {
      int col = wc * 64 + n * 16 + l15;
      int cpos = lg ^ (col & 7);
      bh[n] = *reinterpret_cast<const short8*>(&Bsm[col * 64 + cpos * 8]);
      bl[n] = *reinterpret_cast<const short8*>(&Bsm[col * 64 + (cpos ^ 4) * 8]);
    }
#pragma unroll
    for (int m = 0; m < 4; m++)
#pragma unroll
      for (int n = 0; n < 4; n++) {
        acc[m][n] = MFMA16(ah[m], bh[n], acc[m][n]);
        acc[m][n] = MFMA16(ah[m], bl[n], acc[m][n]);
        acc[m][n] = MFMA16(al[m], bh[n], acc[m][n]);
      }
    __syncthreads();
  }

#pragma unroll
  for (int m = 0; m < 4; m++)
#pragma unroll
    for (int j = 0; j < 4; j++) {
      int row = m0 + wr * 64 + m * 16 + lg * 4 + j;
#pragma unroll
      for (int n = 0; n < 4; n++)
        C[(size_t)row * Nn + n0 + wc * 64 + n * 16 + l15] = acc[m][n][j];
    }
}

// ---------------- RoPE + bf16 hi/lo split + head-major scatter ----------------
__global__ __launch_bounds__(256) void rope_split_kernel(
    const float* __restrict__ qkv, const float* __restrict__ cos_t,
    const float* __restrict__ sin_t, const float* __restrict__ cos_h,
    const float* __restrict__ sin_h, const float* __restrict__ cos_w,
    const float* __restrict__ sin_w, const int* __restrict__ t_idx,
    const int* __restrict__ h_idx, const int* __restrict__ w_idx,
    ushort* __restrict__ Qhi, ushort* __restrict__ Qlo, ushort* __restrict__ Khi,
    ushort* __restrict__ Klo, ushort* __restrict__ Vt) {
  const int tok = blockIdx.x;  // 0..B*N-1
  const int b = tok >> 11, n = tok & 2047;
  const int ti = t_idx[n], hi = h_idx[n], wi = w_idx[n];
  const float* base = qkv + (size_t)tok * C3;

#pragma unroll
  for (int s = 0; s < 3; s++) {
    int j = threadIdx.x + s * 256;
    float c, sn, sign;
    int pj;
    if (j < 192) {
      int jj = j;
      c = cos_t[ti * 192 + jj];
      sn = sin_t[ti * 192 + jj];
      pj = (jj < 96) ? j + 96 : j - 96;
      sign = (jj < 96) ? -1.f : 1.f;
    } else if (j < 480) {
      int jj = j - 192;
      c = cos_h[hi * 288 + jj];
      sn = sin_h[hi * 288 + jj];
      pj = (jj < 144) ? j + 144 : j - 144;
      sign = (jj < 144) ? -1.f : 1.f;
    } else {
      int jj = j - 480;
      c = cos_w[wi * 288 + jj];
      sn = sin_w[wi * 288 + jj];
      pj = (jj < 144) ? j + 144 : j - 144;
      sign = (jj < 144) ? -1.f : 1.f;
    }
    float qv = base[j], kv = base[768 + j], vv = base[1536 + j];
    float qp = base[pj] * sign, kp = base[768 + pj] * sign;
    float qr = fmaf(qv, c, qp * sn) * 0.125f;  // pre-scale by 1/sqrt(64)
    float kr = fmaf(kv, c, kp * sn);
    int h = j >> 6, d = j & 63;
    int bh = b * NHEAD + h;
    size_t o = ((size_t)bh * NN + n) * HD + d;
    ushort qh = f2bf(qr);
    Qhi[o] = qh;
    Qlo[o] = f2bf(qr - bf2f(qh));
    ushort kh = f2bf(kr);
    Khi[o] = kh;
    Klo[o] = f2bf(kr - bf2f(kh));
    Vt[((size_t)bh * HD + d) * NN + n] = f2bf(vv);
  }
}

// ---------------- bf16 MFMA flash attention, swapped-QK^T ----------------
// S^T = MFMA(K, Q): lane holds q = lane&15, k = g*16 + (lane>>4)*4 + j.
// Softmax fully lane-local + 2 shfl; P redistributed to PV B-frag via a
// 4-lane butterfly (2 rounds x 4 u32 shfl_xor). O^T = MFMA(V^T, P).
// K/V staged via global_load_lds (128B rows, chunk^=(row&7) swizzle,
// pre-swizzled source), double-buffered.
__global__ __launch_bounds__(256, 3) void attn_mfma_kernel(
    const ushort* __restrict__ Qhi, const ushort* __restrict__ Qlo,
    const ushort* __restrict__ Khi, const ushort* __restrict__ Klo,
    const ushort* __restrict__ Vt, ushort* __restrict__ AttnS) {
  __shared__ __align__(16) ushort smem[2][3][4096];  // [buf][Kh,Kl,V][64*64]
  const int tid = threadIdx.x;
  const int lane = tid & 63, w = tid >> 6;
  const int l15 = lane & 15, lg = lane >> 4;
  const int qt = blockIdx.x;  // 0..31
  const int bh = blockIdx.y;  // 0..23
  const int b = bh / NHEAD, h = bh % NHEAD;
  const size_t kbase = (size_t)bh * NN * HD;  // Khi/Klo token-major
  const size_t vbase = (size_t)bh * HD * NN;  // Vt d-major

  // Q fragments (B-operand: row=q=l15, k-chunk lg*8), Q pre-scaled by 1/8
  short8 qh[2], ql[2];
  {
    const int r = qt * 64 + w * 16 + l15;
#pragma unroll
    for (int s = 0; s < 2; s++) {
      qh[s] = *reinterpret_cast<const short8*>(Qhi + kbase + (size_t)r * HD + s * 32 + lg * 8);
      ql[s] = *reinterpret_cast<const short8*>(Qlo + kbase + (size_t)r * HD + s * 32 + lg * 8);
    }
  }

  const int srow = lane >> 3;        // staging row-within-group 0..7
  const int sc = (lane & 7) ^ srow;  // pre-swizzled logical chunk

#define STAGE(kt_, bb_)                                                                \
  {                                                                                    \
    _Pragma("unroll") for (int it = 0; it < 2; it++) {                                 \
      int r0 = it * 32 + w * 8;                                                        \
      int r = r0 + srow;                                                               \
      gload_lds16(Khi + kbase + (size_t)((kt_)*64 + r) * 64 + sc * 8,                  \
                  &smem[bb_][0][r0 * 64]);                                             \
      gload_lds16(Klo + kbase + (size_t)((kt_)*64 + r) * 64 + sc * 8,                  \
                  &smem[bb_][1][r0 * 64]);                                             \
      gload_lds16(Vt + vbase + (size_t)r * NN + (kt_)*64 + sc * 8,                     \
                  &smem[bb_][2][r0 * 64]);                                             \
    }                                                                                  \
  }

  f32x4 o_acc[4];
#pragma unroll
  for (int g = 0; g < 4; g++) o_acc[g] = (f32x4){0.f, 0.f, 0.f, 0.f};
  float m_run = -INFINITY, l_run = 0.f;

  STAGE(0, 0);
  __syncthreads();

  const int rmask7 = l15 & 7;
  const int gsel0 = (lg < 2) ? 0 : 1;  // kept g-pair {gsel0, gsel0+2}
  const bool send_own = ((lg ^ (lg >> 1)) & 1) != 0;

  for (int kt = 0; kt < NN / 64; kt++) {
    const int cur = kt & 1;
    if (kt < NN / 64 - 1) STAGE(kt + 1, cur ^ 1);

    const ushort* KhB = smem[cur][0];
    const ushort* KlB = smem[cur][1];
    const ushort* VsB = smem[cur][2];

    // ---- S^T = K Q^T (split bf16): s_acc[g] rows k=g*16+lg*4+j, col q=l15
    f32x4 s_acc[4];
#pragma unroll
    for (int g = 0; g < 4; g++) s_acc[g] = (f32x4){0.f, 0.f, 0.f, 0.f};
#pragma unroll
    for (int g = 0; g < 4; g++) {
      const int r = g * 16 + l15;
#pragma unroll
      for (int s = 0; s < 2; s++) {
        const int cpos = (s * 4 + lg) ^ rmask7;
        short8 ka = *reinterpret_cast<const short8*>(&KhB[r * 64 + cpos * 8]);
        short8 kal = *reinterpret_cast<const short8*>(&KlB[r * 64 + cpos * 8]);
        s_acc[g] = MFMA16(ka, qh[s], s_acc[g]);
        s_acc[g] = MFMA16(kal, qh[s], s_acc[g]);
        s_acc[g] = MFMA16(ka, ql[s], s_acc[g]);
      }
    }

    // ---- lane-local softmax over 16 k-values, reduce across 4 lg-lanes ----
    float pm = -INFINITY;
#pragma unroll
    for (int g = 0; g < 4; g++)
#pragma unroll
      for (int j = 0; j < 4; j++) pm = fmaxf(pm, s_acc[g][j]);
    pm = fmaxf(pm, __shfl_xor(pm, 16, 64));
    pm = fmaxf(pm, __shfl_xor(pm, 32, 64));
    const float mn = fmaxf(m_run, pm);
    const float corr = __expf(m_run - mn);
    m_run = mn;
    float rs = 0.f;
    float p[4][4];
#pragma unroll
    for (int g = 0; g < 4; g++)
#pragma unroll
      for (int j = 0; j < 4; j++) {
        p[g][j] = __expf(s_acc[g][j] - mn);
        rs += p[g][j];
      }
    rs += __shfl_xor(rs, 16, 64);
    rs += __shfl_xor(rs, 32, 64);
    l_run = l_run * corr + rs;
#pragma unroll
    for (int g = 0; g < 4; g++)
#pragma unroll
      for (int j = 0; j < 4; j++) o_acc[g][j] *= corr;

    // ---- pack P to bf16 pairs: w0/w1 per g ----
    unsigned w0[4], w1[4];
#pragma unroll
    for (int g = 0; g < 4; g++) {
      w0[g] = cvt_pk_bf16(p[g][0], p[g][1]);
      w1[g] = cvt_pk_bf16(p[g][2], p[g][3]);
    }

    // ---- 4-lane butterfly: gather P[q=l15][k-chunks] for PV B-frags ----
    const int c0 = gsel0 ^ 1, c1 = c0 + 2;  // complement g-pair
    // round 1: partner lane^32; send complement pair, keep own gsel pair
    unsigned o0 = w0[gsel0], o1 = w1[gsel0], o2 = w0[gsel0 + 2], o3 = w1[gsel0 + 2];
    unsigned r0v = __shfl_xor((int)w0[c0], 32, 64);
    unsigned r1v = __shfl_xor((int)w1[c0], 32, 64);
    unsigned r2v = __shfl_xor((int)w0[c1], 32, 64);
    unsigned r3v = __shfl_xor((int)w1[c1], 32, 64);
    // round 2: partner lane^16; payload = send_own ? own : recv, keep other
    unsigned p0 = send_own ? o0 : r0v, p1 = send_own ? o1 : r1v;
    unsigned p2 = send_own ? o2 : r2v, p3 = send_own ? o3 : r3v;
    unsigned k0v = send_own ? r0v : o0, k1v = send_own ? r1v : o1;
    unsigned k2v = send_own ? r2v : o2, k3v = send_own ? r3v : o3;
    unsigned n0 = __shfl_xor((int)p0, 16, 64);
    unsigned n1 = __shfl_xor((int)p1, 16, 64);
    unsigned n2 = __shfl_xor((int)p2, 16, 64);
    unsigned n3 = __shfl_xor((int)p3, 16, 64);
    // assemble B-frags: kept holds src s0 for even lg, s1 for odd lg
    const bool lgeven = (lg & 1) == 0;
    uint4v bv0 = lgeven ? (uint4v){k0v, k1v, n0, n1} : (uint4v){n0, n1, k0v, k1v};
    uint4v bv1 = lgeven ? (uint4v){k2v, k3v, n2, n3} : (uint4v){n2, n3, k2v, k3v};
    short8 pb[2] = {__builtin_bit_cast(short8, bv0), __builtin_bit_cast(short8, bv1)};

    // ---- O^T += V^T P^T : o_acc[g] rows d=g*16+lg*4+j, col q=l15 ----
#pragma unroll
    for (int kk = 0; kk < 2; kk++) {
#pragma unroll
      for (int g = 0; g < 4; g++) {
        const int cpos = (kk * 4 + lg) ^ rmask7;
        short8 va =
            *reinterpret_cast<const short8*>(&VsB[(g * 16 + l15) * 64 + cpos * 8]);
        o_acc[g] = MFMA16(va, pb[kk], o_acc[g]);
      }
    }
    __syncthreads();
  }

  // ---- epilogue: normalize, split hi/lo, write AttnS [tok][2][768] ----
  const float inv = 1.0f / l_run;
  const int n = qt * 64 + w * 16 + l15;
  const size_t rowb = (size_t)(b * NN + n) * 1536;
#pragma unroll
  for (int g = 0; g < 4; g++) {
    float v0 = o_acc[g][0] * inv, v1 = o_acc[g][1] * inv;
    float v2 = o_acc[g][2] * inv, v3 = o_acc[g][3] * inv;
    ushort h0 = f2bf(v0), h1 = f2bf(v1), h2 = f2bf(v2), h3 = f2bf(v3);
    unsigned hi01 = (unsigned)h0 | ((unsigned)h1 << 16);
    unsigned hi23 = (unsigned)h2 | ((unsigned)h3 << 16);
    unsigned lo01 = cvt_pk_bf16(v0 - bf2f(h0), v1 - bf2f(h1));
    unsigned lo23 = cvt_pk_bf16(v2 - bf2f(h2), v3 - bf2f(h3));
    const int col = h * 64 + g * 16 + lg * 4;
    *reinterpret_cast<uint2*>(AttnS + rowb + col) = make_uint2(hi01, hi23);
    *reinterpret_cast<uint2*>(AttnS + rowb + 768 + col) = make_uint2(lo01, lo23);
  }
#undef STAGE
}

// ---------------- launch ----------------
extern "C" void kernel_launch(void* const* d_in, const int* in_sizes, int n_in,
                              void* d_out, int out_size, void* d_ws, size_t ws_size,
                              hipStream_t stream) {
  const float* x = (const float*)d_in[0];
  const float* Wqkv = (const float*)d_in[1];
  const float* Wout = (const float*)d_in[2];
  const float* cos_t = (const float*)d_in[3];
  const float* sin_t = (const float*)d_in[4];
  const float* cos_h = (const float*)d_in[5];
  const float* sin_h = (const float*)d_in[6];
  const float* cos_w = (const float*)d_in[7];
  const float* sin_w = (const float*)d_in[8];
  const int* t_idx = (const int*)d_in[9];
  const int* h_idx = (const int*)d_in[10];
  const int* w_idx = (const int*)d_in[11];
  float* out = (float*)d_out;

  float* ws = (float*)d_ws;
  float* qkv = ws;  // 4096*2304 fp32
  ushort* us = (ushort*)(qkv + (size_t)4096 * 2304);
  const size_t HS = (size_t)24 * 2048 * 64;
  ushort* Qhi = us;
  ushort* Qlo = Qhi + HS;
  ushort* Khi = Qlo + HS;
  ushort* Klo = Khi + HS;
  ushort* Vt = Klo + HS;
  ushort* xs = Vt + HS;                      // 4096*1536
  ushort* wqs = xs + (size_t)4096 * 1536;    // 2304*1536
  ushort* wos = wqs + (size_t)2304 * 1536;   // 768*1536
  ushort* attns = wos + (size_t)768 * 1536;  // 4096*1536

  // input conversions
  split_rows_kernel<<<dim3(4096 * 192 / 256), 256, 0, stream>>>(x, xs);
  split_transpose_kernel<<<dim3(C3 / 32, CC / 32), 256, 0, stream>>>(Wqkv, wqs, C3);
  split_transpose_kernel<<<dim3(CC / 32, CC / 32), 256, 0, stream>>>(Wout, wos, CC);
  // qkv = x @ Wqkv  (split-bf16 MFMA)
  gemm_split_kernel<<<dim3(C3 / 128, 4096 / 128), 256, 0, stream>>>(xs, wqs, qkv, C3);
  // RoPE + bf16 split + scatter
  rope_split_kernel<<<dim3(BB * NN), 256, 0, stream>>>(qkv, cos_t, sin_t, cos_h, sin_h,
                                                       cos_w, sin_w, t_idx, h_idx, w_idx,
                                                       Qhi, Qlo, Khi, Klo, Vt);
  // flash attention (swapped-QK^T bf16 MFMA), emits split bf16 directly
  attn_mfma_kernel<<<dim3(NN / 64, BB * NHEAD), 256, 0, stream>>>(Qhi, Qlo, Khi, Klo, Vt,
                                                                  attns);
  // out = attn @ Wout  (split-bf16 MFMA)
  gemm_split_kernel<<<dim3(CC / 128, 4096 / 128), 256, 0, stream>>>(attns, wos, out, CC);
}

// Round 6
// 213.062 us; speedup vs baseline: 3.7036x; 1.0020x over previous
//
#include <hip/hip_runtime.h>
#include <hip/hip_bf16.h>
#include <math.h>

// Problem constants
#define BB 2
#define NN 2048
#define CC 768
#define NHEAD 12
#define HD 64
#define C3 2304

typedef __attribute__((ext_vector_type(8))) short short8;
typedef __attribute__((ext_vector_type(4))) float f32x4;
typedef __attribute__((ext_vector_type(4))) unsigned uint4v;
#define MFMA16(a, b, c) __builtin_amdgcn_mfma_f32_16x16x32_bf16(a, b, c, 0, 0, 0)

__device__ __forceinline__ float fast_exp2(float x) {
  return __builtin_amdgcn_exp2f(x);  // v_exp_f32 (natively 2^x)
}

__device__ __forceinline__ ushort f2bf(float x) {
  unsigned u = __builtin_bit_cast(unsigned, x);
  u += 0x7fffu + ((u >> 16) & 1u);
  return (ushort)(u >> 16);
}
__device__ __forceinline__ float bf2f(ushort h) {
  return __builtin_bit_cast(float, (unsigned)h << 16);
}
__device__ __forceinline__ unsigned cvt_pk_bf16(float lo, float hi) {
  unsigned r;
  asm("v_cvt_pk_bf16_f32 %0, %1, %2" : "=v"(r) : "v"(lo), "v"(hi));
  return r;
}

__device__ __forceinline__ void gload_lds16(const void* gsrc, void* lds) {
  __builtin_amdgcn_global_load_lds(
      (const __attribute__((address_space(1))) unsigned int*)gsrc,
      (__attribute__((address_space(3))) unsigned int*)lds, 16, 0, 0);
}

// ---------------- input split kernels ----------------
__global__ __launch_bounds__(256) void split_rows_kernel(const float* __restrict__ X,
                                                         ushort* __restrict__ Xs) {
  int idx = blockIdx.x * 256 + threadIdx.x;  // 4096*192 total
  int m = idx / 192, c4 = (idx % 192) * 4;
  float4 v = *reinterpret_cast<const float4*>(&X[(size_t)m * 768 + c4]);
  float vals[4] = {v.x, v.y, v.z, v.w};
  ushort hs[4], ls[4];
#pragma unroll
  for (int i = 0; i < 4; i++) {
    hs[i] = f2bf(vals[i]);
    ls[i] = f2bf(vals[i] - bf2f(hs[i]));
  }
  size_t o = (size_t)m * 1536 + c4;
  *reinterpret_cast<ushort4*>(&Xs[o]) = make_ushort4(hs[0], hs[1], hs[2], hs[3]);
  *reinterpret_cast<ushort4*>(&Xs[o + 768]) = make_ushort4(ls[0], ls[1], ls[2], ls[3]);
}

__global__ __launch_bounds__(256) void split_transpose_kernel(const float* __restrict__ W,
                                                              ushort* __restrict__ Ws,
                                                              int N) {
  __shared__ float t[32][33];
  const int tx = threadIdx.x & 31, ty = threadIdx.x >> 5;  // 32 x 8
  const int n0 = blockIdx.x * 32, k0 = blockIdx.y * 32;
#pragma unroll
  for (int r = 0; r < 4; r++) {
    int kk = ty + r * 8;
    t[kk][tx] = W[(size_t)(k0 + kk) * N + n0 + tx];
  }
  __syncthreads();
#pragma unroll
  for (int r = 0; r < 4; r++) {
    int nn = ty + r * 8;
    float v = t[tx][nn];
    ushort hi = f2bf(v);
    ushort lo = f2bf(v - bf2f(hi));
    size_t o = (size_t)(n0 + nn) * 1536 + k0 + tx;
    Ws[o] = hi;
    Ws[o + 768] = lo;
  }
}

// ---------------- split-bf16 MFMA GEMM (unchanged) ----------------
__global__ __launch_bounds__(256) void gemm_split_kernel(const ushort* __restrict__ A,
                                                         const ushort* __restrict__ B,
                                                         float* __restrict__ C, int Nn) {
  __shared__ __align__(16) ushort Asm[128 * 64];
  __shared__ __align__(16) ushort Bsm[128 * 64];
  const int tid = threadIdx.x;
  const int lane = tid & 63, w = tid >> 6;
  const int l15 = lane & 15, lg = lane >> 4;
  const int wr = w >> 1, wc = w & 1;
  const int m0 = blockIdx.y * 128, n0 = blockIdx.x * 128;
  const int lrow = lane >> 3, lc = lane & 7;

  f32x4 acc[4][4];
#pragma unroll
  for (int m = 0; m < 4; m++)
#pragma unroll
    for (int n = 0; n < 4; n++) acc[m][n] = (f32x4){0.f, 0.f, 0.f, 0.f};

  for (int k0 = 0; k0 < 768; k0 += 32) {
#pragma unroll
    for (int it = 0; it < 4; it++) {
      int r0 = it * 32 + w * 8;
      int row = r0 + lrow;
      int cp = lc ^ (row & 7);
      size_t goff = (size_t)row * 1536 + (cp >> 2) * 768 + k0 + (cp & 3) * 8;
      gload_lds16(A + (size_t)m0 * 1536 + goff, &Asm[r0 * 64]);
      gload_lds16(B + (size_t)n0 * 1536 + goff, &Bsm[r0 * 64]);
    }
    __syncthreads();

    short8 ah[4], al[4], bh[4], bl[4];
#pragma unroll
    for (int m = 0; m < 4; m++) {
      int row = wr * 64 + m * 16 + l15;
      int cpos = lg ^ (row & 7);
      ah[m] = *reinterpret_cast<const short8*>(&Asm[row * 64 + cpos * 8]);
      al[m] = *reinterpret_cast<const short8*>(&Asm[row * 64 + (cpos ^ 4) * 8]);
    }
#pragma unroll
    for (int n = 0; n < 4; n++) {
      int col = wc * 64 + n * 16 + l15;
      int cpos = lg ^ (col & 7);
      bh[n] = *reinterpret_cast<const short8*>(&Bsm[col * 64 + cpos * 8]);
      bl[n] = *reinterpret_cast<const short8*>(&Bsm[col * 64 + (cpos ^ 4) * 8]);
    }
#pragma unroll
    for (int m = 0; m < 4; m++)
#pragma unroll
      for (int n = 0; n < 4; n++) {
        acc[m][n] = MFMA16(ah[m], bh[n], acc[m][n]);
        acc[m][n] = MFMA16(ah[m], bl[n], acc[m][n]);
        acc[m][n] = MFMA16(al[m], bh[n], acc[m][n]);
      }
    __syncthreads();
  }

#pragma unroll
  for (int m = 0; m < 4; m++)
#pragma unroll
    for (int j = 0; j < 4; j++) {
      int row = m0 + wr * 64 + m * 16 + lg * 4 + j;
#pragma unroll
      for (int n = 0; n < 4; n++)
        C[(size_t)row * Nn + n0 + wc * 64 + n * 16 + l15] = acc[m][n][j];
    }
}

// ---------------- RoPE + bf16 hi/lo split + head-major scatter ----------------
// Q pre-scaled by (1/8)*log2(e) so attn softmax runs in exp2 domain.
__global__ __launch_bounds__(256) void rope_split_kernel(
    const float* __restrict__ qkv, const float* __restrict__ cos_t,
    const float* __restrict__ sin_t, const float* __restrict__ cos_h,
    const float* __restrict__ sin_h, const float* __restrict__ cos_w,
    const float* __restrict__ sin_w, const int* __restrict__ t_idx,
    const int* __restrict__ h_idx, const int* __restrict__ w_idx,
    ushort* __restrict__ Qhi, ushort* __restrict__ Qlo, ushort* __restrict__ Khi,
    ushort* __restrict__ Klo, ushort* __restrict__ Vt) {
  const int tok = blockIdx.x;  // 0..B*N-1
  const int b = tok >> 11, n = tok & 2047;
  const int ti = t_idx[n], hi = h_idx[n], wi = w_idx[n];
  const float* base = qkv + (size_t)tok * C3;
  const float QSC = 0.125f * 1.44269504088896f;  // 1/sqrt(64) * log2(e)

#pragma unroll
  for (int s = 0; s < 3; s++) {
    int j = threadIdx.x + s * 256;
    float c, sn, sign;
    int pj;
    if (j < 192) {
      int jj = j;
      c = cos_t[ti * 192 + jj];
      sn = sin_t[ti * 192 + jj];
      pj = (jj < 96) ? j + 96 : j - 96;
      sign = (jj < 96) ? -1.f : 1.f;
    } else if (j < 480) {
      int jj = j - 192;
      c = cos_h[hi * 288 + jj];
      sn = sin_h[hi * 288 + jj];
      pj = (jj < 144) ? j + 144 : j - 144;
      sign = (jj < 144) ? -1.f : 1.f;
    } else {
      int jj = j - 480;
      c = cos_w[wi * 288 + jj];
      sn = sin_w[wi * 288 + jj];
      pj = (jj < 144) ? j + 144 : j - 144;
      sign = (jj < 144) ? -1.f : 1.f;
    }
    float qv = base[j], kv = base[768 + j], vv = base[1536 + j];
    float qp = base[pj] * sign, kp = base[768 + pj] * sign;
    float qr = fmaf(qv, c, qp * sn) * QSC;
    float kr = fmaf(kv, c, kp * sn);
    int h = j >> 6, d = j & 63;
    int bh = b * NHEAD + h;
    size_t o = ((size_t)bh * NN + n) * HD + d;
    ushort qh = f2bf(qr);
    Qhi[o] = qh;
    Qlo[o] = f2bf(qr - bf2f(qh));
    ushort kh = f2bf(kr);
    Khi[o] = kh;
    Klo[o] = f2bf(kr - bf2f(kh));
    Vt[((size_t)bh * HD + d) * NN + n] = f2bf(vv);
  }
}

// ---------------- bf16 MFMA flash attention, swapped-QK^T, split-K ----------------
// blockIdx.z selects half the k-range (16 of 32 tiles). Single-buffer 24KB LDS
// -> 6 blocks/CU; 1536 blocks = 6/CU evenly. exp2-domain softmax, defer-max
// THR=8, setprio around MFMA. Writes fp32 partials (O^T, m, l).
__global__ __launch_bounds__(256, 6) void attn_mfma_kernel(
    const ushort* __restrict__ Qhi, const ushort* __restrict__ Qlo,
    const ushort* __restrict__ Khi, const ushort* __restrict__ Klo,
    const ushort* __restrict__ Vt, float* __restrict__ PartO,
    float* __restrict__ Partml) {
  __shared__ __align__(16) ushort smem[3][4096];  // [Kh,Kl,V][64*64]
  const int tid = threadIdx.x;
  const int lane = tid & 63, w = tid >> 6;
  const int l15 = lane & 15, lg = lane >> 4;
  const int qt = blockIdx.x;   // 0..31
  const int bh = blockIdx.y;   // 0..23
  const int sp = blockIdx.z;   // 0..1 (k-range split)
  const size_t kbase = (size_t)bh * NN * HD;  // Khi/Klo token-major
  const size_t vbase = (size_t)bh * HD * NN;  // Vt d-major

  // Q fragments (B-operand: row=q=l15, k-chunk lg*8)
  short8 qh[2], ql[2];
  {
    const int r = qt * 64 + w * 16 + l15;
#pragma unroll
    for (int s = 0; s < 2; s++) {
      qh[s] = *reinterpret_cast<const short8*>(Qhi + kbase + (size_t)r * HD + s * 32 + lg * 8);
      ql[s] = *reinterpret_cast<const short8*>(Qlo + kbase + (size_t)r * HD + s * 32 + lg * 8);
    }
  }

  const int srow = lane >> 3;        // staging row-within-group 0..7
  const int sc = (lane & 7) ^ srow;  // pre-swizzled logical chunk

#define STAGE(kt_)                                                             \
  {                                                                            \
    _Pragma("unroll") for (int it = 0; it < 2; it++) {                         \
      int r0 = it * 32 + w * 8;                                                \
      int r = r0 + srow;                                                       \
      gload_lds16(Khi + kbase + (size_t)((kt_)*64 + r) * 64 + sc * 8,          \
                  &smem[0][r0 * 64]);                                          \
      gload_lds16(Klo + kbase + (size_t)((kt_)*64 + r) * 64 + sc * 8,          \
                  &smem[1][r0 * 64]);                                          \
      gload_lds16(Vt + vbase + (size_t)r * NN + (kt_)*64 + sc * 8,             \
                  &smem[2][r0 * 64]);                                          \
    }                                                                          \
  }

  f32x4 o_acc[4];
#pragma unroll
  for (int g = 0; g < 4; g++) o_acc[g] = (f32x4){0.f, 0.f, 0.f, 0.f};
  float m_run = -INFINITY, l_run = 0.f;

  const int rmask7 = l15 & 7;
  const int gsel0 = (lg < 2) ? 0 : 1;  // kept g-pair {gsel0, gsel0+2}
  const bool send_own = ((lg ^ (lg >> 1)) & 1) != 0;

  for (int kt = sp * 16; kt < sp * 16 + 16; kt++) {
    STAGE(kt);
    __syncthreads();

    const ushort* KhB = smem[0];
    const ushort* KlB = smem[1];
    const ushort* VsB = smem[2];

    // ---- S^T = K Q^T (split bf16): s_acc[g] rows k=g*16+lg*4+j, col q=l15
    f32x4 s_acc[4];
#pragma unroll
    for (int g = 0; g < 4; g++) s_acc[g] = (f32x4){0.f, 0.f, 0.f, 0.f};
    __builtin_amdgcn_s_setprio(1);
#pragma unroll
    for (int g = 0; g < 4; g++) {
      const int r = g * 16 + l15;
#pragma unroll
      for (int s = 0; s < 2; s++) {
        const int cpos = (s * 4 + lg) ^ rmask7;
        short8 ka = *reinterpret_cast<const short8*>(&KhB[r * 64 + cpos * 8]);
        short8 kal = *reinterpret_cast<const short8*>(&KlB[r * 64 + cpos * 8]);
        s_acc[g] = MFMA16(ka, qh[s], s_acc[g]);
        s_acc[g] = MFMA16(kal, qh[s], s_acc[g]);
        s_acc[g] = MFMA16(ka, ql[s], s_acc[g]);
      }
    }
    __builtin_amdgcn_s_setprio(0);

    // ---- softmax (exp2 domain), defer-max THR=8 ----
    float pm = -INFINITY;
#pragma unroll
    for (int g = 0; g < 4; g++)
#pragma unroll
      for (int j = 0; j < 4; j++) pm = fmaxf(pm, s_acc[g][j]);
    pm = fmaxf(pm, __shfl_xor(pm, 16, 64));
    pm = fmaxf(pm, __shfl_xor(pm, 32, 64));
    if (!__all(pm - m_run <= 8.0f)) {
      const float mn = fmaxf(m_run, pm);
      const float corr = fast_exp2(m_run - mn);
      m_run = mn;
      l_run *= corr;
#pragma unroll
      for (int g = 0; g < 4; g++)
#pragma unroll
        for (int j = 0; j < 4; j++) o_acc[g][j] *= corr;
    }
    float rs = 0.f;
    float p[4][4];
#pragma unroll
    for (int g = 0; g < 4; g++)
#pragma unroll
      for (int j = 0; j < 4; j++) {
        p[g][j] = fast_exp2(s_acc[g][j] - m_run);
        rs += p[g][j];
      }
    rs += __shfl_xor(rs, 16, 64);
    rs += __shfl_xor(rs, 32, 64);
    l_run += rs;

    // ---- pack P to bf16 pairs ----
    unsigned w0[4], w1[4];
#pragma unroll
    for (int g = 0; g < 4; g++) {
      w0[g] = cvt_pk_bf16(p[g][0], p[g][1]);
      w1[g] = cvt_pk_bf16(p[g][2], p[g][3]);
    }

    // ---- 4-lane butterfly: gather P[q=l15][k-chunks] for PV B-frags ----
    const int c0 = gsel0 ^ 1, c1 = c0 + 2;
    unsigned o0 = w0[gsel0], o1 = w1[gsel0], o2 = w0[gsel0 + 2], o3 = w1[gsel0 + 2];
    unsigned r0v = __shfl_xor((int)w0[c0], 32, 64);
    unsigned r1v = __shfl_xor((int)w1[c0], 32, 64);
    unsigned r2v = __shfl_xor((int)w0[c1], 32, 64);
    unsigned r3v = __shfl_xor((int)w1[c1], 32, 64);
    unsigned p0 = send_own ? o0 : r0v, p1 = send_own ? o1 : r1v;
    unsigned p2 = send_own ? o2 : r2v, p3 = send_own ? o3 : r3v;
    unsigned k0v = send_own ? r0v : o0, k1v = send_own ? r1v : o1;
    unsigned k2v = send_own ? r2v : o2, k3v = send_own ? r3v : o3;
    unsigned n0 = __shfl_xor((int)p0, 16, 64);
    unsigned n1 = __shfl_xor((int)p1, 16, 64);
    unsigned n2 = __shfl_xor((int)p2, 16, 64);
    unsigned n3 = __shfl_xor((int)p3, 16, 64);
    const bool lgeven = (lg & 1) == 0;
    uint4v bv0 = lgeven ? (uint4v){k0v, k1v, n0, n1} : (uint4v){n0, n1, k0v, k1v};
    uint4v bv1 = lgeven ? (uint4v){k2v, k3v, n2, n3} : (uint4v){n2, n3, k2v, k3v};
    short8 pb[2] = {__builtin_bit_cast(short8, bv0), __builtin_bit_cast(short8, bv1)};

    // ---- O^T += V^T P^T : o_acc[g] rows d=g*16+lg*4+j, col q=l15 ----
    __builtin_amdgcn_s_setprio(1);
#pragma unroll
    for (int kk = 0; kk < 2; kk++) {
#pragma unroll
      for (int g = 0; g < 4; g++) {
        const int cpos = (kk * 4 + lg) ^ rmask7;
        short8 va =
            *reinterpret_cast<const short8*>(&VsB[(g * 16 + l15) * 64 + cpos * 8]);
        o_acc[g] = MFMA16(va, pb[kk], o_acc[g]);
      }
    }
    __builtin_amdgcn_s_setprio(0);
    __syncthreads();
  }

  // ---- write fp32 partials: PartO [sp][bh][q][64d], Partml [sp][bh][q][2] ----
  const int q = qt * 64 + w * 16 + l15;
  const size_t pidx = ((size_t)(sp * 24 + bh) * NN + q);
#pragma unroll
  for (int g = 0; g < 4; g++) {
    *reinterpret_cast<float4*>(&PartO[pidx * 64 + g * 16 + lg * 4]) =
        make_float4(o_acc[g][0], o_acc[g][1], o_acc[g][2], o_acc[g][3]);
  }
  if (lg == 0) {
    Partml[pidx * 2] = m_run;
    Partml[pidx * 2 + 1] = l_run;
  }
#undef STAGE
}

// ---------------- split-K combine: merge 2 partials, emit split-bf16 attns ----
__global__ __launch_bounds__(256) void attn_combine_kernel(
    const float* __restrict__ PartO, const float* __restrict__ Partml,
    ushort* __restrict__ AttnS) {
  const int qt = blockIdx.x;  // 0..31
  const int bh = blockIdx.y;  // 0..23
  const int b = bh / NHEAD, h = bh % NHEAD;
  const int tid = threadIdx.x;
  const int q = qt * 64 + (tid >> 2);
  const int d0 = (tid & 3) * 16;
  const size_t i0 = ((size_t)bh * NN + q);
  const size_t i1 = ((size_t)(24 + bh) * NN + q);
  const float m0 = Partml[i0 * 2], l0 = Partml[i0 * 2 + 1];
  const float m1 = Partml[i1 * 2], l1 = Partml[i1 * 2 + 1];
  const float m = fmaxf(m0, m1);
  const float w0 = fast_exp2(m0 - m), w1 = fast_exp2(m1 - m);
  const float inv = 1.0f / (l0 * w0 + l1 * w1);

  ushort hi[16], lo[16];
#pragma unroll
  for (int d = 0; d < 16; d += 4) {
    float4 a = *reinterpret_cast<const float4*>(&PartO[i0 * 64 + d0 + d]);
    float4 bvv = *reinterpret_cast<const float4*>(&PartO[i1 * 64 + d0 + d]);
    float vals[4] = {(a.x * w0 + bvv.x * w1) * inv, (a.y * w0 + bvv.y * w1) * inv,
                     (a.z * w0 + bvv.z * w1) * inv, (a.w * w0 + bvv.w * w1) * inv};
#pragma unroll
    for (int i = 0; i < 4; i++) {
      ushort hh = f2bf(vals[i]);
      hi[d + i] = hh;
      lo[d + i] = f2bf(vals[i] - bf2f(hh));
    }
  }
  const size_t rowb = (size_t)(b * NN + q) * 1536;
  const int col = h * 64 + d0;
  *reinterpret_cast<uint4*>(AttnS + rowb + col) = *reinterpret_cast<uint4*>(hi);
  *reinterpret_cast<uint4*>(AttnS + rowb + col + 8) = *reinterpret_cast<uint4*>(hi + 8);
  *reinterpret_cast<uint4*>(AttnS + rowb + 768 + col) = *reinterpret_cast<uint4*>(lo);
  *reinterpret_cast<uint4*>(AttnS + rowb + 768 + col + 8) =
      *reinterpret_cast<uint4*>(lo + 8);
}

// ---------------- launch ----------------
extern "C" void kernel_launch(void* const* d_in, const int* in_sizes, int n_in,
                              void* d_out, int out_size, void* d_ws, size_t ws_size,
                              hipStream_t stream) {
  const float* x = (const float*)d_in[0];
  const float* Wqkv = (const float*)d_in[1];
  const float* Wout = (const float*)d_in[2];
  const float* cos_t = (const float*)d_in[3];
  const float* sin_t = (const float*)d_in[4];
  const float* cos_h = (const float*)d_in[5];
  const float* sin_h = (const float*)d_in[6];
  const float* cos_w = (const float*)d_in[7];
  const float* sin_w = (const float*)d_in[8];
  const int* t_idx = (const int*)d_in[9];
  const int* h_idx = (const int*)d_in[10];
  const int* w_idx = (const int*)d_in[11];
  float* out = (float*)d_out;

  float* ws = (float*)d_ws;
  float* qkv = ws;  // 4096*2304 fp32; reused as PartO after rope consumes it
  float* PartO = qkv;  // 2*24*2048*64 = 6.29M fp32 (fits in qkv's 9.44M)
  ushort* us = (ushort*)(qkv + (size_t)4096 * 2304);
  const size_t HS = (size_t)24 * 2048 * 64;
  ushort* Qhi = us;
  ushort* Qlo = Qhi + HS;
  ushort* Khi = Qlo + HS;
  ushort* Klo = Khi + HS;
  ushort* Vt = Klo + HS;
  ushort* xs = Vt + HS;                      // 4096*1536
  ushort* wqs = xs + (size_t)4096 * 1536;    // 2304*1536
  ushort* wos = wqs + (size_t)2304 * 1536;   // 768*1536
  ushort* attns = wos + (size_t)768 * 1536;  // 4096*1536
  float* Partml = (float*)(attns + (size_t)4096 * 1536);  // 2*24*2048*2 fp32

  // input conversions
  split_rows_kernel<<<dim3(4096 * 192 / 256), 256, 0, stream>>>(x, xs);
  split_transpose_kernel<<<dim3(C3 / 32, CC / 32), 256, 0, stream>>>(Wqkv, wqs, C3);
  split_transpose_kernel<<<dim3(CC / 32, CC / 32), 256, 0, stream>>>(Wout, wos, CC);
  // qkv = x @ Wqkv  (split-bf16 MFMA)
  gemm_split_kernel<<<dim3(C3 / 128, 4096 / 128), 256, 0, stream>>>(xs, wqs, qkv, C3);
  // RoPE + bf16 split + scatter
  rope_split_kernel<<<dim3(BB * NN), 256, 0, stream>>>(qkv, cos_t, sin_t, cos_h, sin_h,
                                                       cos_w, sin_w, t_idx, h_idx, w_idx,
                                                       Qhi, Qlo, Khi, Klo, Vt);
  // flash attention (swapped-QK^T bf16 MFMA, split-K=2) -> fp32 partials
  attn_mfma_kernel<<<dim3(NN / 64, BB * NHEAD, 2), 256, 0, stream>>>(
      Qhi, Qlo, Khi, Klo, Vt, PartO, Partml);
  // combine partials -> split-bf16 attns
  attn_combine_kernel<<<dim3(NN / 64, BB * NHEAD), 256, 0, stream>>>(PartO, Partml,
                                                                     attns);
  // out = attn @ Wout  (split-bf16 MFMA)
  gemm_split_kernel<<<dim3(CC / 128, 4096 / 128), 256, 0, stream>>>(attns, wos, out, CC);
}

// Round 7
// 195.786 us; speedup vs baseline: 4.0304x; 1.0882x over previous
//
#include <hip/hip_runtime.h>
#include <hip/hip_bf16.h>
#include <math.h>

// Problem constants
#define BB 2
#define NN 2048
#define CC 768
#define NHEAD 12
#define HD 64
#define C3 2304

typedef __attribute__((ext_vector_type(8))) short short8;
typedef __attribute__((ext_vector_type(4))) float f32x4;
typedef __attribute__((ext_vector_type(4))) unsigned uint4v;
#define MFMA16(a, b, c) __builtin_amdgcn_mfma_f32_16x16x32_bf16(a, b, c, 0, 0, 0)

__device__ __forceinline__ float fast_exp2(float x) {
  return __builtin_amdgcn_exp2f(x);  // v_exp_f32 (natively 2^x)
}

__device__ __forceinline__ ushort f2bf(float x) {
  unsigned u = __builtin_bit_cast(unsigned, x);
  u += 0x7fffu + ((u >> 16) & 1u);
  return (ushort)(u >> 16);
}
__device__ __forceinline__ float bf2f(ushort h) {
  return __builtin_bit_cast(float, (unsigned)h << 16);
}
__device__ __forceinline__ unsigned cvt_pk_bf16(float lo, float hi) {
  unsigned r;
  asm("v_cvt_pk_bf16_f32 %0, %1, %2" : "=v"(r) : "v"(lo), "v"(hi));
  return r;
}

__device__ __forceinline__ void gload_lds16(const void* gsrc, void* lds) {
  __builtin_amdgcn_global_load_lds(
      (const __attribute__((address_space(1))) unsigned int*)gsrc,
      (__attribute__((address_space(3))) unsigned int*)lds, 16, 0, 0);
}

// ---------------- input split kernels ----------------
__global__ __launch_bounds__(256) void split_rows_kernel(const float* __restrict__ X,
                                                         ushort* __restrict__ Xs) {
  int idx = blockIdx.x * 256 + threadIdx.x;  // 4096*192 total
  int m = idx / 192, c4 = (idx % 192) * 4;
  float4 v = *reinterpret_cast<const float4*>(&X[(size_t)m * 768 + c4]);
  float vals[4] = {v.x, v.y, v.z, v.w};
  ushort hs[4], ls[4];
#pragma unroll
  for (int i = 0; i < 4; i++) {
    hs[i] = f2bf(vals[i]);
    ls[i] = f2bf(vals[i] - bf2f(hs[i]));
  }
  size_t o = (size_t)m * 1536 + c4;
  *reinterpret_cast<ushort4*>(&Xs[o]) = make_ushort4(hs[0], hs[1], hs[2], hs[3]);
  *reinterpret_cast<ushort4*>(&Xs[o + 768]) = make_ushort4(ls[0], ls[1], ls[2], ls[3]);
}

__global__ __launch_bounds__(256) void split_transpose_kernel(const float* __restrict__ W,
                                                              ushort* __restrict__ Ws,
                                                              int N) {
  __shared__ float t[32][33];
  const int tx = threadIdx.x & 31, ty = threadIdx.x >> 5;  // 32 x 8
  const int n0 = blockIdx.x * 32, k0 = blockIdx.y * 32;
#pragma unroll
  for (int r = 0; r < 4; r++) {
    int kk = ty + r * 8;
    t[kk][tx] = W[(size_t)(k0 + kk) * N + n0 + tx];
  }
  __syncthreads();
#pragma unroll
  for (int r = 0; r < 4; r++) {
    int nn = ty + r * 8;
    float v = t[tx][nn];
    ushort hi = f2bf(v);
    ushort lo = f2bf(v - bf2f(hi));
    size_t o = (size_t)(n0 + nn) * 1536 + k0 + tx;
    Ws[o] = hi;
    Ws[o + 768] = lo;
  }
}

// ---------------- split-bf16 MFMA GEMM, BN=96, templated BM ----------------
// A: [M][2][768] bf16 hi/lo, B: [N][2][768] bf16 hi/lo (pre-transposed),
// C: [M][N] fp32 = A@B (3-term split). 4 waves in a 2x2 grid; wave tile
// (BM/2)x48. Grid sized for exact blocks/CU: QKV BM=128 -> 768 blk (3/CU),
// out-proj BM=64 -> 512 blk (2/CU).
template <int BM>
__global__ __launch_bounds__(256) void gemm_split_kernel(const ushort* __restrict__ A,
                                                         const ushort* __restrict__ B,
                                                         float* __restrict__ C, int Nn) {
  constexpr int BN = 96;
  constexpr int WM = BM / 2;   // 64 or 32
  constexpr int MR = WM / 16;  // 4 or 2
  constexpr int NR = 3;        // 48/16
  __shared__ __align__(16) ushort Asm[BM * 64];
  __shared__ __align__(16) ushort Bsm[BN * 64];
  const int tid = threadIdx.x;
  const int lane = tid & 63, w = tid >> 6;
  const int l15 = lane & 15, lg = lane >> 4;
  const int wr = w >> 1, wc = w & 1;
  const int m0 = blockIdx.y * BM, n0 = blockIdx.x * BN;
  const int lrow = lane >> 3, lc = lane & 7;

  f32x4 acc[MR][NR];
#pragma unroll
  for (int m = 0; m < MR; m++)
#pragma unroll
    for (int n = 0; n < NR; n++) acc[m][n] = (f32x4){0.f, 0.f, 0.f, 0.f};

  for (int k0 = 0; k0 < 768; k0 += 32) {
#pragma unroll
    for (int it = 0; it < BM / 32; it++) {
      int r0 = it * 32 + w * 8;
      int row = r0 + lrow;
      int cp = lc ^ (row & 7);
      size_t goff = (size_t)row * 1536 + (cp >> 2) * 768 + k0 + (cp & 3) * 8;
      gload_lds16(A + (size_t)m0 * 1536 + goff, &Asm[r0 * 64]);
    }
#pragma unroll
    for (int it = 0; it < BN / 32; it++) {
      int r0 = it * 32 + w * 8;
      int row = r0 + lrow;
      int cp = lc ^ (row & 7);
      size_t goff = (size_t)row * 1536 + (cp >> 2) * 768 + k0 + (cp & 3) * 8;
      gload_lds16(B + (size_t)n0 * 1536 + goff, &Bsm[r0 * 64]);
    }
    __syncthreads();

    short8 ah[MR], al[MR], bh[NR], bl[NR];
#pragma unroll
    for (int m = 0; m < MR; m++) {
      int row = wr * WM + m * 16 + l15;
      int cpos = lg ^ (row & 7);
      ah[m] = *reinterpret_cast<const short8*>(&Asm[row * 64 + cpos * 8]);
      al[m] = *reinterpret_cast<const short8*>(&Asm[row * 64 + (cpos ^ 4) * 8]);
    }
#pragma unroll
    for (int n = 0; n < NR; n++) {
      int col = wc * 48 + n * 16 + l15;
      int cpos = lg ^ (col & 7);
      bh[n] = *reinterpret_cast<const short8*>(&Bsm[col * 64 + cpos * 8]);
      bl[n] = *reinterpret_cast<const short8*>(&Bsm[col * 64 + (cpos ^ 4) * 8]);
    }
#pragma unroll
    for (int m = 0; m < MR; m++)
#pragma unroll
      for (int n = 0; n < NR; n++) {
        acc[m][n] = MFMA16(ah[m], bh[n], acc[m][n]);
        acc[m][n] = MFMA16(ah[m], bl[n], acc[m][n]);
        acc[m][n] = MFMA16(al[m], bh[n], acc[m][n]);
      }
    __syncthreads();
  }

#pragma unroll
  for (int m = 0; m < MR; m++)
#pragma unroll
    for (int j = 0; j < 4; j++) {
      int row = m0 + wr * WM + m * 16 + lg * 4 + j;
#pragma unroll
      for (int n = 0; n < NR; n++)
        C[(size_t)row * Nn + n0 + wc * 48 + n * 16 + l15] = acc[m][n][j];
    }
}

// ---------------- RoPE + bf16 hi/lo split + head-major scatter ----------------
// Q pre-scaled by (1/8)*log2(e) so attn softmax runs in exp2 domain.
__global__ __launch_bounds__(256) void rope_split_kernel(
    const float* __restrict__ qkv, const float* __restrict__ cos_t,
    const float* __restrict__ sin_t, const float* __restrict__ cos_h,
    const float* __restrict__ sin_h, const float* __restrict__ cos_w,
    const float* __restrict__ sin_w, const int* __restrict__ t_idx,
    const int* __restrict__ h_idx, const int* __restrict__ w_idx,
    ushort* __restrict__ Qhi, ushort* __restrict__ Qlo, ushort* __restrict__ Khi,
    ushort* __restrict__ Klo, ushort* __restrict__ Vt) {
  const int tok = blockIdx.x;  // 0..B*N-1
  const int b = tok >> 11, n = tok & 2047;
  const int ti = t_idx[n], hi = h_idx[n], wi = w_idx[n];
  const float* base = qkv + (size_t)tok * C3;
  const float QSC = 0.125f * 1.44269504088896f;  // 1/sqrt(64) * log2(e)

#pragma unroll
  for (int s = 0; s < 3; s++) {
    int j = threadIdx.x + s * 256;
    float c, sn, sign;
    int pj;
    if (j < 192) {
      int jj = j;
      c = cos_t[ti * 192 + jj];
      sn = sin_t[ti * 192 + jj];
      pj = (jj < 96) ? j + 96 : j - 96;
      sign = (jj < 96) ? -1.f : 1.f;
    } else if (j < 480) {
      int jj = j - 192;
      c = cos_h[hi * 288 + jj];
      sn = sin_h[hi * 288 + jj];
      pj = (jj < 144) ? j + 144 : j - 144;
      sign = (jj < 144) ? -1.f : 1.f;
    } else {
      int jj = j - 480;
      c = cos_w[wi * 288 + jj];
      sn = sin_w[wi * 288 + jj];
      pj = (jj < 144) ? j + 144 : j - 144;
      sign = (jj < 144) ? -1.f : 1.f;
    }
    float qv = base[j], kv = base[768 + j], vv = base[1536 + j];
    float qp = base[pj] * sign, kp = base[768 + pj] * sign;
    float qr = fmaf(qv, c, qp * sn) * QSC;
    float kr = fmaf(kv, c, kp * sn);
    int h = j >> 6, d = j & 63;
    int bh = b * NHEAD + h;
    size_t o = ((size_t)bh * NN + n) * HD + d;
    ushort qh = f2bf(qr);
    Qhi[o] = qh;
    Qlo[o] = f2bf(qr - bf2f(qh));
    ushort kh = f2bf(kr);
    Khi[o] = kh;
    Klo[o] = f2bf(kr - bf2f(kh));
    Vt[((size_t)bh * HD + d) * NN + n] = f2bf(vv);
  }
}

// ---------------- bf16 MFMA flash attention, swapped-QK^T, split-K ----------------
__global__ __launch_bounds__(256, 6) void attn_mfma_kernel(
    const ushort* __restrict__ Qhi, const ushort* __restrict__ Qlo,
    const ushort* __restrict__ Khi, const ushort* __restrict__ Klo,
    const ushort* __restrict__ Vt, float* __restrict__ PartO,
    float* __restrict__ Partml) {
  __shared__ __align__(16) ushort smem[3][4096];  // [Kh,Kl,V][64*64]
  const int tid = threadIdx.x;
  const int lane = tid & 63, w = tid >> 6;
  const int l15 = lane & 15, lg = lane >> 4;
  const int qt = blockIdx.x;   // 0..31
  const int bh = blockIdx.y;   // 0..23
  const int sp = blockIdx.z;   // 0..1 (k-range split)
  const size_t kbase = (size_t)bh * NN * HD;  // Khi/Klo token-major
  const size_t vbase = (size_t)bh * HD * NN;  // Vt d-major

  // Q fragments (B-operand: row=q=l15, k-chunk lg*8)
  short8 qh[2], ql[2];
  {
    const int r = qt * 64 + w * 16 + l15;
#pragma unroll
    for (int s = 0; s < 2; s++) {
      qh[s] = *reinterpret_cast<const short8*>(Qhi + kbase + (size_t)r * HD + s * 32 + lg * 8);
      ql[s] = *reinterpret_cast<const short8*>(Qlo + kbase + (size_t)r * HD + s * 32 + lg * 8);
    }
  }

  const int srow = lane >> 3;        // staging row-within-group 0..7
  const int sc = (lane & 7) ^ srow;  // pre-swizzled logical chunk

#define STAGE(kt_)                                                             \
  {                                                                            \
    _Pragma("unroll") for (int it = 0; it < 2; it++) {                         \
      int r0 = it * 32 + w * 8;                                                \
      int r = r0 + srow;                                                       \
      gload_lds16(Khi + kbase + (size_t)((kt_)*64 + r) * 64 + sc * 8,          \
                  &smem[0][r0 * 64]);                                          \
      gload_lds16(Klo + kbase + (size_t)((kt_)*64 + r) * 64 + sc * 8,          \
                  &smem[1][r0 * 64]);                                          \
      gload_lds16(Vt + vbase + (size_t)r * NN + (kt_)*64 + sc * 8,             \
                  &smem[2][r0 * 64]);                                          \
    }                                                                          \
  }

  f32x4 o_acc[4];
#pragma unroll
  for (int g = 0; g < 4; g++) o_acc[g] = (f32x4){0.f, 0.f, 0.f, 0.f};
  float m_run = -INFINITY, l_run = 0.f;  // l_run is a per-lane partial

  const int rmask7 = l15 & 7;
  const int gsel0 = (lg < 2) ? 0 : 1;  // kept g-pair {gsel0, gsel0+2}
  const bool send_own = ((lg ^ (lg >> 1)) & 1) != 0;

  for (int kt = sp * 16; kt < sp * 16 + 16; kt++) {
    STAGE(kt);
    __syncthreads();

    const ushort* KhB = smem[0];
    const ushort* KlB = smem[1];
    const ushort* VsB = smem[2];

    // ---- S^T = K Q^T (split bf16): s_acc[g] rows k=g*16+lg*4+j, col q=l15
    f32x4 s_acc[4];
#pragma unroll
    for (int g = 0; g < 4; g++) s_acc[g] = (f32x4){0.f, 0.f, 0.f, 0.f};
    __builtin_amdgcn_s_setprio(1);
#pragma unroll
    for (int g = 0; g < 4; g++) {
      const int r = g * 16 + l15;
#pragma unroll
      for (int s = 0; s < 2; s++) {
        const int cpos = (s * 4 + lg) ^ rmask7;
        short8 ka = *reinterpret_cast<const short8*>(&KhB[r * 64 + cpos * 8]);
        short8 kal = *reinterpret_cast<const short8*>(&KlB[r * 64 + cpos * 8]);
        s_acc[g] = MFMA16(ka, qh[s], s_acc[g]);
        s_acc[g] = MFMA16(kal, qh[s], s_acc[g]);
        s_acc[g] = MFMA16(ka, ql[s], s_acc[g]);
      }
    }
    __builtin_amdgcn_s_setprio(0);

    // ---- softmax (exp2 domain), defer-max THR=8 ----
    float pm = -INFINITY;
#pragma unroll
    for (int g = 0; g < 4; g++)
#pragma unroll
      for (int j = 0; j < 4; j++) pm = fmaxf(pm, s_acc[g][j]);
    pm = fmaxf(pm, __shfl_xor(pm, 16, 64));
    pm = fmaxf(pm, __shfl_xor(pm, 32, 64));
    if (!__all(pm - m_run <= 8.0f)) {
      const float mn = fmaxf(m_run, pm);
      const float corr = fast_exp2(m_run - mn);  // uniform within q-column group
      m_run = mn;
      l_run *= corr;
#pragma unroll
      for (int g = 0; g < 4; g++)
#pragma unroll
        for (int j = 0; j < 4; j++) o_acc[g][j] *= corr;
    }
    float p[4][4];
#pragma unroll
    for (int g = 0; g < 4; g++)
#pragma unroll
      for (int j = 0; j < 4; j++) {
        p[g][j] = fast_exp2(s_acc[g][j] - m_run);
        l_run += p[g][j];  // per-lane partial; cross-lane reduce at epilogue
      }

    // ---- pack P to bf16 pairs ----
    unsigned w0[4], w1[4];
#pragma unroll
    for (int g = 0; g < 4; g++) {
      w0[g] = cvt_pk_bf16(p[g][0], p[g][1]);
      w1[g] = cvt_pk_bf16(p[g][2], p[g][3]);
    }

    // ---- 4-lane butterfly: gather P[q=l15][k-chunks] for PV B-frags ----
    const int c0 = gsel0 ^ 1, c1 = c0 + 2;
    unsigned o0 = w0[gsel0], o1 = w1[gsel0], o2 = w0[gsel0 + 2], o3 = w1[gsel0 + 2];
    unsigned r0v = __shfl_xor((int)w0[c0], 32, 64);
    unsigned r1v = __shfl_xor((int)w1[c0], 32, 64);
    unsigned r2v = __shfl_xor((int)w0[c1], 32, 64);
    unsigned r3v = __shfl_xor((int)w1[c1], 32, 64);
    unsigned p0 = send_own ? o0 : r0v, p1 = send_own ? o1 : r1v;
    unsigned p2 = send_own ? o2 : r2v, p3 = send_own ? o3 : r3v;
    unsigned k0v = send_own ? r0v : o0, k1v = send_own ? r1v : o1;
    unsigned k2v = send_own ? r2v : o2, k3v = send_own ? r3v : o3;
    unsigned n0 = __shfl_xor((int)p0, 16, 64);
    unsigned n1 = __shfl_xor((int)p1, 16, 64);
    unsigned n2 = __shfl_xor((int)p2, 16, 64);
    unsigned n3 = __shfl_xor((int)p3, 16, 64);
    const bool lgeven = (lg & 1) == 0;
    uint4v bv0 = lgeven ? (uint4v){k0v, k1v, n0, n1} : (uint4v){n0, n1, k0v, k1v};
    uint4v bv1 = lgeven ? (uint4v){k2v, k3v, n2, n3} : (uint4v){n2, n3, k2v, k3v};
    short8 pb[2] = {__builtin_bit_cast(short8, bv0), __builtin_bit_cast(short8, bv1)};

    // ---- O^T += V^T P^T : o_acc[g] rows d=g*16+lg*4+j, col q=l15 ----
    __builtin_amdgcn_s_setprio(1);
#pragma unroll
    for (int kk = 0; kk < 2; kk++) {
#pragma unroll
      for (int g = 0; g < 4; g++) {
        const int cpos = (kk * 4 + lg) ^ rmask7;
        short8 va =
            *reinterpret_cast<const short8*>(&VsB[(g * 16 + l15) * 64 + cpos * 8]);
        o_acc[g] = MFMA16(va, pb[kk], o_acc[g]);
      }
    }
    __builtin_amdgcn_s_setprio(0);
    __syncthreads();
  }

  // ---- epilogue: reduce l across the 4 q-column lanes, write partials ----
  l_run += __shfl_xor(l_run, 16, 64);
  l_run += __shfl_xor(l_run, 32, 64);
  const int q = qt * 64 + w * 16 + l15;
  const size_t pidx = ((size_t)(sp * 24 + bh) * NN + q);
#pragma unroll
  for (int g = 0; g < 4; g++) {
    *reinterpret_cast<float4*>(&PartO[pidx * 64 + g * 16 + lg * 4]) =
        make_float4(o_acc[g][0], o_acc[g][1], o_acc[g][2], o_acc[g][3]);
  }
  if (lg == 0) {
    Partml[pidx * 2] = m_run;
    Partml[pidx * 2 + 1] = l_run;
  }
#undef STAGE
}

// ---------------- split-K combine: merge 2 partials, emit split-bf16 attns ----
__global__ __launch_bounds__(256) void attn_combine_kernel(
    const float* __restrict__ PartO, const float* __restrict__ Partml,
    ushort* __restrict__ AttnS) {
  const int qt = blockIdx.x;  // 0..31
  const int bh = blockIdx.y;  // 0..23
  const int b = bh / NHEAD, h = bh % NHEAD;
  const int tid = threadIdx.x;
  const int q = qt * 64 + (tid >> 2);
  const int d0 = (tid & 3) * 16;
  const size_t i0 = ((size_t)bh * NN + q);
  const size_t i1 = ((size_t)(24 + bh) * NN + q);
  const float m0 = Partml[i0 * 2], l0 = Partml[i0 * 2 + 1];
  const float m1 = Partml[i1 * 2], l1 = Partml[i1 * 2 + 1];
  const float m = fmaxf(m0, m1);
  const float w0 = fast_exp2(m0 - m), w1 = fast_exp2(m1 - m);
  const float inv = 1.0f / (l0 * w0 + l1 * w1);

  ushort hi[16], lo[16];
#pragma unroll
  for (int d = 0; d < 16; d += 4) {
    float4 a = *reinterpret_cast<const float4*>(&PartO[i0 * 64 + d0 + d]);
    float4 bvv = *reinterpret_cast<const float4*>(&PartO[i1 * 64 + d0 + d]);
    float vals[4] = {(a.x * w0 + bvv.x * w1) * inv, (a.y * w0 + bvv.y * w1) * inv,
                     (a.z * w0 + bvv.z * w1) * inv, (a.w * w0 + bvv.w * w1) * inv};
#pragma unroll
    for (int i = 0; i < 4; i++) {
      ushort hh = f2bf(vals[i]);
      hi[d + i] = hh;
      lo[d + i] = f2bf(vals[i] - bf2f(hh));
    }
  }
  const size_t rowb = (size_t)(b * NN + q) * 1536;
  const int col = h * 64 + d0;
  *reinterpret_cast<uint4*>(AttnS + rowb + col) = *reinterpret_cast<uint4*>(hi);
  *reinterpret_cast<uint4*>(AttnS + rowb + col + 8) = *reinterpret_cast<uint4*>(hi + 8);
  *reinterpret_cast<uint4*>(AttnS + rowb + 768 + col) = *reinterpret_cast<uint4*>(lo);
  *reinterpret_cast<uint4*>(AttnS + rowb + 768 + col + 8) =
      *reinterpret_cast<uint4*>(lo + 8);
}

// ---------------- launch ----------------
extern "C" void kernel_launch(void* const* d_in, const int* in_sizes, int n_in,
                              void* d_out, int out_size, void* d_ws, size_t ws_size,
                              hipStream_t stream) {
  const float* x = (const float*)d_in[0];
  const float* Wqkv = (const float*)d_in[1];
  const float* Wout = (const float*)d_in[2];
  const float* cos_t = (const float*)d_in[3];
  const float* sin_t = (const float*)d_in[4];
  const float* cos_h = (const float*)d_in[5];
  const float* sin_h = (const float*)d_in[6];
  const float* cos_w = (const float*)d_in[7];
  const float* sin_w = (const float*)d_in[8];
  const int* t_idx = (const int*)d_in[9];
  const int* h_idx = (const int*)d_in[10];
  const int* w_idx = (const int*)d_in[11];
  float* out = (float*)d_out;

  float* ws = (float*)d_ws;
  float* qkv = ws;  // 4096*2304 fp32; reused as PartO after rope consumes it
  float* PartO = qkv;  // 2*24*2048*64 = 6.29M fp32 (fits in qkv's 9.44M)
  ushort* us = (ushort*)(qkv + (size_t)4096 * 2304);
  const size_t HS = (size_t)24 * 2048 * 64;
  ushort* Qhi = us;
  ushort* Qlo = Qhi + HS;
  ushort* Khi = Qlo + HS;
  ushort* Klo = Khi + HS;
  ushort* Vt = Klo + HS;
  ushort* xs = Vt + HS;                      // 4096*1536
  ushort* wqs = xs + (size_t)4096 * 1536;    // 2304*1536
  ushort* wos = wqs + (size_t)2304 * 1536;   // 768*1536
  ushort* attns = wos + (size_t)768 * 1536;  // 4096*1536
  float* Partml = (float*)(attns + (size_t)4096 * 1536);  // 2*24*2048*2 fp32

  // input conversions
  split_rows_kernel<<<dim3(4096 * 192 / 256), 256, 0, stream>>>(x, xs);
  split_transpose_kernel<<<dim3(C3 / 32, CC / 32), 256, 0, stream>>>(Wqkv, wqs, C3);
  split_transpose_kernel<<<dim3(CC / 32, CC / 32), 256, 0, stream>>>(Wout, wos, CC);
  // qkv = x @ Wqkv  (split-bf16 MFMA, 128x96 tiles -> 768 blocks = 3/CU)
  gemm_split_kernel<128><<<dim3(C3 / 96, 4096 / 128), 256, 0, stream>>>(xs, wqs, qkv, C3);
  // RoPE + bf16 split + scatter
  rope_split_kernel<<<dim3(BB * NN), 256, 0, stream>>>(qkv, cos_t, sin_t, cos_h, sin_h,
                                                       cos_w, sin_w, t_idx, h_idx, w_idx,
                                                       Qhi, Qlo, Khi, Klo, Vt);
  // flash attention (swapped-QK^T bf16 MFMA, split-K=2) -> fp32 partials
  attn_mfma_kernel<<<dim3(NN / 64, BB * NHEAD, 2), 256, 0, stream>>>(
      Qhi, Qlo, Khi, Klo, Vt, PartO, Partml);
  // combine partials -> split-bf16 attns
  attn_combine_kernel<<<dim3(NN / 64, BB * NHEAD), 256, 0, stream>>>(PartO, Partml,
                                                                     attns);
  // out = attn @ Wout  (split-bf16 MFMA, 64x96 tiles -> 512 blocks = 2/CU)
  gemm_split_kernel<64><<<dim3(CC / 96, 4096 / 64), 256, 0, stream>>>(attns, wos, out, CC);
}